// Round 1
// baseline (785.034 us; speedup 1.0000x reference)
//
#include <hip/hip_runtime.h>

typedef unsigned short u16;
typedef __bf16 bf16x8 __attribute__((ext_vector_type(8)));
typedef float f32x4 __attribute__((ext_vector_type(4)));

__device__ __forceinline__ u16 f2bf(float f) {
    unsigned u = __float_as_uint(f);
    u = (u + 0x7FFFu + ((u >> 16) & 1u)) >> 16;
    return (u16)u;
}
__device__ __forceinline__ float bf2f(u16 h) {
    return __uint_as_float(((unsigned)h) << 16);
}

// ---------------- convert fp32 -> bf16 (flat) ----------------
__global__ __launch_bounds__(256) void cvt_kernel(const float* __restrict__ in,
                                                  u16* __restrict__ out, long n) {
    long i = ((long)blockIdx.x * blockDim.x + threadIdx.x) * 4;
    if (i + 3 < n) {
        float4 v = *(const float4*)&in[i];
        __align__(8) u16 r[4] = {f2bf(v.x), f2bf(v.y), f2bf(v.z), f2bf(v.w)};
        *(int2*)&out[i] = *(const int2*)r;
    }
}

// ---------------- transpose (+convert) -> bf16 ----------------
// in [R][C] -> out [C][R]
template <int INF32>
__global__ __launch_bounds__(256) void transpose_to_bf16(const void* __restrict__ in,
                                                         u16* __restrict__ out, int R, int C,
                                                         long inB, long outB) {
    __shared__ float tile[32][33];
    const long zi = (long)blockIdx.z * inB;
    const long zo = (long)blockIdx.z * outB;
    const int c0 = blockIdx.x * 32, r0 = blockIdx.y * 32;
    const int tx = threadIdx.x & 31;
    const int ty = threadIdx.x >> 5;  // 0..7
#pragma unroll
    for (int i = 0; i < 32; i += 8) {
        long idx = zi + (long)(r0 + ty + i) * C + c0 + tx;
        float v = INF32 ? ((const float*)in)[idx] : bf2f(((const u16*)in)[idx]);
        tile[ty + i][tx] = v;
    }
    __syncthreads();
#pragma unroll
    for (int i = 0; i < 32; i += 8) {
        out[zo + (long)(c0 + ty + i) * R + r0 + tx] = f2bf(tile[tx][ty + i]);
    }
}

// ---------------- generic NT bf16 MFMA GEMM ----------------
// C[M,N] = scale * (A[M,K] @ B[N,K]^T) + bias, optional relu.
// A, B row-major bf16 with K contiguous. OUTBF: 1 -> bf16 out, 0 -> f32 out.
#define BM 128
#define BN 128
#define BKK 64
#define KP 72  // padded LDS row stride in shorts (144B: 2-way-only bank aliasing)

template <int OUTBF>
__global__ __launch_bounds__(256) void gemm_nt(const u16* __restrict__ A,
                                               const u16* __restrict__ Bm,
                                               void* __restrict__ Cout, int M, int N, int K,
                                               long sA, long sB, long sC,
                                               const float* __restrict__ bias, int relu,
                                               float scale) {
    __shared__ __align__(16) u16 As[BM * KP];
    __shared__ __align__(16) u16 Bs[BN * KP];
    const int tid = threadIdx.x;
    const int lane = tid & 63;
    const int wid = tid >> 6;
    const int wr = wid >> 1, wc = wid & 1;
    const int l15 = lane & 15, lg = lane >> 4;
    const long zA = (long)blockIdx.z * sA;
    const long zB = (long)blockIdx.z * sB;
    const long zC = (long)blockIdx.z * sC;
    const int m0 = blockIdx.y * BM, n0 = blockIdx.x * BN;

    f32x4 acc[4][4] = {};

    const int srow = tid >> 3;  // 0..31
    const int skc = tid & 7;    // 0..7  (8 shorts per chunk, BK=64 -> 8 chunks/row)

    for (int k0 = 0; k0 < K; k0 += BKK) {
#pragma unroll
        for (int i = 0; i < 4; ++i) {
            int row = srow + 32 * i;
            int4 v = *(const int4*)(A + zA + (long)(m0 + row) * K + k0 + skc * 8);
            *(int4*)&As[row * KP + skc * 8] = v;
        }
#pragma unroll
        for (int i = 0; i < 4; ++i) {
            int row = srow + 32 * i;
            int4 v = *(const int4*)(Bm + zB + (long)(n0 + row) * K + k0 + skc * 8);
            *(int4*)&Bs[row * KP + skc * 8] = v;
        }
        __syncthreads();
#pragma unroll
        for (int kk = 0; kk < 2; ++kk) {
            bf16x8 af[4], bfr[4];
#pragma unroll
            for (int m = 0; m < 4; ++m)
                af[m] = *(const bf16x8*)&As[(wr * 64 + m * 16 + l15) * KP + kk * 32 + lg * 8];
#pragma unroll
            for (int n = 0; n < 4; ++n)
                bfr[n] = *(const bf16x8*)&Bs[(wc * 64 + n * 16 + l15) * KP + kk * 32 + lg * 8];
#pragma unroll
            for (int m = 0; m < 4; ++m)
#pragma unroll
                for (int n = 0; n < 4; ++n)
                    acc[m][n] =
                        __builtin_amdgcn_mfma_f32_16x16x32_bf16(af[m], bfr[n], acc[m][n], 0, 0, 0);
        }
        __syncthreads();
    }

#pragma unroll
    for (int n = 0; n < 4; ++n) {
        const int col = n0 + wc * 64 + n * 16 + l15;
        const float bv = bias ? bias[col] : 0.0f;
#pragma unroll
        for (int m = 0; m < 4; ++m) {
#pragma unroll
            for (int r = 0; r < 4; ++r) {
                const int row = m0 + wr * 64 + m * 16 + lg * 4 + r;
                float v = acc[m][n][r] * scale + bv;
                if (relu) v = fmaxf(v, 0.0f);
                if (OUTBF)
                    ((u16*)Cout)[zC + (long)row * N + col] = f2bf(v);
                else
                    ((float*)Cout)[zC + (long)row * N + col] = v;
            }
        }
    }
}

// ---------------- LayerNorm (bf16 in/out, in-place), one block per row ----------------
__global__ __launch_bounds__(256) void ln_kernel(u16* __restrict__ x, const float* __restrict__ g,
                                                 const float* __restrict__ be, int D) {
    const int tid = threadIdx.x;
    u16* p = x + (long)blockIdx.x * D;
    const int E = D >> 8;  // 8 (D=2048) or 4 (D=1024)
    __align__(16) u16 raw[8];
    if (E == 8)
        *(int4*)raw = *(const int4*)&p[tid * 8];
    else
        *(int2*)raw = *(const int2*)&p[tid * 4];
    float s = 0.f, ss = 0.f;
#pragma unroll
    for (int i = 0; i < 8; ++i) {
        if (i < E) {
            float f = bf2f(raw[i]);
            s += f;
            ss += f * f;
        }
    }
#pragma unroll
    for (int o = 32; o > 0; o >>= 1) {
        s += __shfl_down(s, o);
        ss += __shfl_down(ss, o);
    }
    __shared__ float sh[8];
    const int wid = tid >> 6;
    if ((tid & 63) == 0) {
        sh[wid] = s;
        sh[wid + 4] = ss;
    }
    __syncthreads();
    s = sh[0] + sh[1] + sh[2] + sh[3];
    ss = sh[4] + sh[5] + sh[6] + sh[7];
    const float inv = 1.0f / (float)D;
    const float mu = s * inv;
    const float var = ss * inv - mu * mu;
    const float rs = rsqrtf(var + 1e-5f);
#pragma unroll
    for (int i = 0; i < 8; ++i) {
        if (i < E) {
            int idx = tid * E + i;
            float f = (bf2f(raw[i]) - mu) * rs * g[idx] + be[idx];
            raw[i] = f2bf(f);
        }
    }
    if (E == 8)
        *(int4*)&p[tid * 8] = *(const int4*)raw;
    else
        *(int2*)&p[tid * 4] = *(const int2*)raw;
}

// ---------------- softmax over rows of S=2048, fp32 in/out + bf16 copy ----------------
__global__ __launch_bounds__(256) void softmax_kernel(float* __restrict__ a,
                                                      u16* __restrict__ ab, int S) {
    const int tid = threadIdx.x;
    float* p = a + (long)blockIdx.x * S;
    __align__(16) float v[8];
    *(float4*)&v[0] = *(const float4*)&p[tid * 8];
    *(float4*)&v[4] = *(const float4*)&p[tid * 8 + 4];
    float mx = v[0];
#pragma unroll
    for (int i = 1; i < 8; ++i) mx = fmaxf(mx, v[i]);
#pragma unroll
    for (int o = 32; o > 0; o >>= 1) mx = fmaxf(mx, __shfl_down(mx, o));
    __shared__ float sh[8];
    const int wid = tid >> 6;
    if ((tid & 63) == 0) sh[wid] = mx;
    __syncthreads();
    mx = fmaxf(fmaxf(sh[0], sh[1]), fmaxf(sh[2], sh[3]));
    float s = 0.f;
#pragma unroll
    for (int i = 0; i < 8; ++i) {
        v[i] = expf(v[i] - mx);
        s += v[i];
    }
#pragma unroll
    for (int o = 32; o > 0; o >>= 1) s += __shfl_down(s, o);
    if ((tid & 63) == 0) sh[4 + wid] = s;
    __syncthreads();
    s = sh[4] + sh[5] + sh[6] + sh[7];
    const float inv = 1.0f / s;
    __align__(16) u16 r[8];
#pragma unroll
    for (int i = 0; i < 8; ++i) {
        v[i] *= inv;
        r[i] = f2bf(v[i]);
    }
    *(float4*)&p[tid * 8] = *(const float4*)&v[0];
    *(float4*)&p[tid * 8 + 4] = *(const float4*)&v[4];
    *(int4*)&ab[(long)blockIdx.x * S + tid * 8] = *(const int4*)r;
}

// ---------------- head: attended @ Wh + bh -> gates -> log ----------------
// block 512 = 8 waves; each wave handles one row; lane = output column (C=64).
__global__ __launch_bounds__(512) void logits_kernel(const float* __restrict__ attended,
                                                     const float* __restrict__ Wh,
                                                     const float* __restrict__ bh,
                                                     const float* __restrict__ prior,
                                                     const float* __restrict__ ag,
                                                     const float* __restrict__ og,
                                                     float* __restrict__ out) {
    __shared__ u16 Whs[256 * 64];  // 32KB chunk of Wh as bf16
    const int tid = threadIdx.x;
    const int wid = tid >> 6, lane = tid & 63;
    const long row = (long)blockIdx.x * 8 + wid;
    const float* arow = attended + row * 1024;
    float acc = 0.f;
    for (int kc = 0; kc < 4; ++kc) {
        for (int i = tid; i < 256 * 64; i += 512) Whs[i] = f2bf(Wh[kc * 256 * 64 + i]);
        __syncthreads();
#pragma unroll 4
        for (int k = 0; k < 256; k += 4) {
            float4 a = *(const float4*)&arow[kc * 256 + k];
            acc += a.x * bf2f(Whs[(k + 0) * 64 + lane]);
            acc += a.y * bf2f(Whs[(k + 1) * 64 + lane]);
            acc += a.z * bf2f(Whs[(k + 2) * 64 + lane]);
            acc += a.w * bf2f(Whs[(k + 3) * 64 + lane]);
        }
        __syncthreads();
    }
    const float logit = acc + bh[lane];
    const int b = (int)(row >> 11);
    const float sp = 1.f / (1.f + expf(-prior[b * 64 + lane]));
    const float sl = 1.f / (1.f + expf(-logit));
    const float av = fminf(sl, sp) * ag[lane];
    const float ov = fmaxf(sl, sp) * og[lane];
    out[row * 64 + lane] = logf((av + ov) * 0.5f + 1e-10f);
}

extern "C" void kernel_launch(void* const* d_in, const int* in_sizes, int n_in, void* d_out,
                              int out_size, void* d_ws, size_t ws_size, hipStream_t stream) {
    const float* emb = (const float*)d_in[0];
    const float* prior = (const float*)d_in[1];
    const float* W1 = (const float*)d_in[2];
    const float* b1 = (const float*)d_in[3];
    const float* g1 = (const float*)d_in[4];
    const float* be1 = (const float*)d_in[5];
    const float* W2 = (const float*)d_in[6];
    const float* b2 = (const float*)d_in[7];
    const float* g2 = (const float*)d_in[8];
    const float* be2 = (const float*)d_in[9];
    const float* Wh = (const float*)d_in[10];
    const float* bh = (const float*)d_in[11];
    const float* ag = (const float*)d_in[12];
    const float* og = (const float*)d_in[13];

    const int Bn = 8, S = 2048, DIN = 1024, H1 = 2048, H2 = 1024, Cc = 64;
    const int M = Bn * S;  // 16384

    char* ws = (char*)d_ws;
    size_t off = 0;
    auto alloc = [&](size_t b) {
        size_t o = off;
        off += (b + 255) & ~(size_t)255;
        return o;
    };
    u16* embb = (u16*)(ws + alloc((size_t)M * DIN * 2));
    u16* W1t = (u16*)(ws + alloc((size_t)H1 * DIN * 2));
    u16* W2t = (u16*)(ws + alloc((size_t)H2 * H1 * 2));
    u16* h = (u16*)(ws + alloc((size_t)M * H1 * 2));
    u16* feat = (u16*)(ws + alloc((size_t)M * H2 * 2));
    u16* featT = (u16*)(ws + alloc((size_t)Bn * H2 * S * 2));
    u16* attnb = (u16*)(ws + alloc((size_t)Bn * S * S * 2));
    float* attd = (float*)(ws + alloc((size_t)M * H2 * 4));

    float* out_logits = (float*)d_out;
    float* out_attn = out_logits + (size_t)M * Cc;

    // 1. embeddings -> bf16
    cvt_kernel<<<(int)(((long)M * DIN) / 1024), 256, 0, stream>>>(emb, embb, (long)M * DIN);
    // 2. W1 [DIN][H1] -> W1t [H1][DIN]
    transpose_to_bf16<1><<<dim3(H1 / 32, DIN / 32, 1), 256, 0, stream>>>(W1, W1t, DIN, H1, 0, 0);
    // 3. W2 [H1][H2] -> W2t [H2][H1]
    transpose_to_bf16<1><<<dim3(H2 / 32, H1 / 32, 1), 256, 0, stream>>>(W2, W2t, H1, H2, 0, 0);
    // 4. h = relu(emb @ W1 + b1)   [M,H1] bf16
    gemm_nt<1><<<dim3(H1 / BN, M / BM, 1), 256, 0, stream>>>(embb, W1t, h, M, H1, DIN, 0, 0, 0,
                                                             b1, 1, 1.0f);
    // 5. LN1 in-place
    ln_kernel<<<M, 256, 0, stream>>>(h, g1, be1, H1);
    // 6. feat = relu(h @ W2 + b2)  [M,H2] bf16
    gemm_nt<1><<<dim3(H2 / BN, M / BM, 1), 256, 0, stream>>>(h, W2t, feat, M, H2, H1, 0, 0, 0, b2,
                                                             1, 1.0f);
    // 7. LN2 in-place
    ln_kernel<<<M, 256, 0, stream>>>(feat, g2, be2, H2);
    // 8. featT per batch: [S][H2] -> [H2][S]
    transpose_to_bf16<0><<<dim3(H2 / 32, S / 32, Bn), 256, 0, stream>>>(
        feat, featT, S, H2, (long)S * H2, (long)H2 * S);
    // 9. scores = feat @ feat^T / 32  -> d_out attn region (fp32)
    gemm_nt<0><<<dim3(S / BN, S / BM, Bn), 256, 0, stream>>>(feat, feat, out_attn, S, S, H2,
                                                             (long)S * H2, (long)S * H2,
                                                             (long)S * S, nullptr, 0, 0.03125f);
    // 10. softmax rows (writes fp32 output + bf16 copy)
    softmax_kernel<<<M, 256, 0, stream>>>(out_attn, attnb, S);
    // 11. attended = attn @ feat   [S,H2] fp32 per batch
    gemm_nt<0><<<dim3(H2 / BN, S / BM, Bn), 256, 0, stream>>>(attnb, featT, attd, S, H2, S,
                                                              (long)S * S, (long)H2 * S,
                                                              (long)S * H2, nullptr, 0, 1.0f);
    // 12. head + logic gates + log
    logits_kernel<<<M / 8, 512, 0, stream>>>(attd, Wh, bh, prior, ag, og, out_logits);
}

// Round 2
// 727.698 us; speedup vs baseline: 1.0788x; 1.0788x over previous
//
#include <hip/hip_runtime.h>

typedef unsigned short u16;
typedef __bf16 bf16x8 __attribute__((ext_vector_type(8)));
typedef float f32x4 __attribute__((ext_vector_type(4)));

__device__ __forceinline__ u16 f2bf(float f) {
    unsigned u = __float_as_uint(f);
    u = (u + 0x7FFFu + ((u >> 16) & 1u)) >> 16;
    return (u16)u;
}
__device__ __forceinline__ float bf2f(u16 h) {
    return __uint_as_float(((unsigned)h) << 16);
}

// async global -> LDS, 16B per lane
__device__ __forceinline__ void gld16(const u16* g, u16* l) {
    __builtin_amdgcn_global_load_lds((const __attribute__((address_space(1))) void*)g,
                                     (__attribute__((address_space(3))) void*)l, 16, 0, 0);
}

// ---------------- convert fp32 -> bf16 (flat) ----------------
__global__ __launch_bounds__(256) void cvt_kernel(const float* __restrict__ in,
                                                  u16* __restrict__ out, long n) {
    long i = ((long)blockIdx.x * blockDim.x + threadIdx.x) * 4;
    if (i + 3 < n) {
        float4 v = *(const float4*)&in[i];
        __align__(8) u16 r[4] = {f2bf(v.x), f2bf(v.y), f2bf(v.z), f2bf(v.w)};
        *(int2*)&out[i] = *(const int2*)r;
    }
}

// ---------------- transpose (+convert) -> bf16 ----------------
// in [R][C] -> out [C][R]
template <int INF32>
__global__ __launch_bounds__(256) void transpose_to_bf16(const void* __restrict__ in,
                                                         u16* __restrict__ out, int R, int C,
                                                         long inB, long outB) {
    __shared__ float tile[32][33];
    const long zi = (long)blockIdx.z * inB;
    const long zo = (long)blockIdx.z * outB;
    const int c0 = blockIdx.x * 32, r0 = blockIdx.y * 32;
    const int tx = threadIdx.x & 31;
    const int ty = threadIdx.x >> 5;  // 0..7
#pragma unroll
    for (int i = 0; i < 32; i += 8) {
        long idx = zi + (long)(r0 + ty + i) * C + c0 + tx;
        float v = INF32 ? ((const float*)in)[idx] : bf2f(((const u16*)in)[idx]);
        tile[ty + i][tx] = v;
    }
    __syncthreads();
#pragma unroll
    for (int i = 0; i < 32; i += 8) {
        out[zo + (long)(c0 + ty + i) * R + r0 + tx] = f2bf(tile[tx][ty + i]);
    }
}

// ---------------- generic NT bf16 MFMA GEMM (m97 structure) ----------------
// C[M,N] = scale * (A[M,K] @ B[N,K]^T) + bias, optional relu.
// A, B row-major bf16, K contiguous, K % 64 == 0, rows 16B-aligned.
template <int OUTBF>
__global__ __launch_bounds__(256) void gemm_nt(const u16* __restrict__ A,
                                               const u16* __restrict__ Bm,
                                               void* __restrict__ Cout, int M, int N, int K,
                                               long sA, long sB, long sC,
                                               const float* __restrict__ bias, int relu,
                                               float scale) {
    __shared__ __align__(16) u16 As[128 * 64];
    __shared__ __align__(16) u16 Bs[128 * 64];
    const int tid = threadIdx.x;
    const int lane = tid & 63;
    const int wid = tid >> 6;
    const int wr = wid >> 1, wc = wid & 1;
    const int l15 = lane & 15, lg = lane >> 4;
    const long zA = (long)blockIdx.z * sA;
    const long zB = (long)blockIdx.z * sB;
    const long zC = (long)blockIdx.z * sC;
    const int m0 = blockIdx.y * 128, n0 = blockIdx.x * 128;

    f32x4 acc[4][4] = {};

    const int srow = tid >> 3;        // 0..31
    const int scol = (tid & 7) * 8;   // shorts
    const u16* pa = A + zA + (long)(m0 + srow) * K + scol;
    const u16* pb = Bm + zB + (long)(n0 + srow) * K + scol;

    for (int k0 = 0; k0 < K; k0 += 64) {
#pragma unroll
        for (int i = 0; i < 4; ++i) gld16(pa + (long)i * 32 * K + k0, &As[i * 2048 + tid * 8]);
#pragma unroll
        for (int i = 0; i < 4; ++i) gld16(pb + (long)i * 32 * K + k0, &Bs[i * 2048 + tid * 8]);
        __syncthreads();
#pragma unroll
        for (int kk = 0; kk < 2; ++kk) {
            bf16x8 af[4], bfr[4];
#pragma unroll
            for (int m = 0; m < 4; ++m)
                af[m] = *(const bf16x8*)&As[(wr * 64 + m * 16 + l15) * 64 + kk * 32 + lg * 8];
#pragma unroll
            for (int n = 0; n < 4; ++n)
                bfr[n] = *(const bf16x8*)&Bs[(wc * 64 + n * 16 + l15) * 64 + kk * 32 + lg * 8];
#pragma unroll
            for (int m = 0; m < 4; ++m)
#pragma unroll
                for (int n = 0; n < 4; ++n)
                    acc[m][n] =
                        __builtin_amdgcn_mfma_f32_16x16x32_bf16(af[m], bfr[n], acc[m][n], 0, 0, 0);
        }
        __syncthreads();
    }

#pragma unroll
    for (int n = 0; n < 4; ++n) {
        const int col = n0 + wc * 64 + n * 16 + l15;
        const float bv = bias ? bias[col] : 0.0f;
#pragma unroll
        for (int m = 0; m < 4; ++m) {
#pragma unroll
            for (int r = 0; r < 4; ++r) {
                const int row = m0 + wr * 64 + m * 16 + lg * 4 + r;
                float v = acc[m][n][r] * scale + bv;
                if (relu) v = fmaxf(v, 0.0f);
                if (OUTBF)
                    ((u16*)Cout)[zC + (long)row * N + col] = f2bf(v);
                else
                    ((float*)Cout)[zC + (long)row * N + col] = v;
            }
        }
    }
}

// ---------------- LayerNorm (bf16 in/out, in-place), one block per row ----------------
__global__ __launch_bounds__(256) void ln_kernel(u16* __restrict__ x, const float* __restrict__ g,
                                                 const float* __restrict__ be, int D) {
    const int tid = threadIdx.x;
    u16* p = x + (long)blockIdx.x * D;
    const int E = D >> 8;  // 8 (D=2048) or 4 (D=1024)
    __align__(16) u16 raw[8];
    if (E == 8)
        *(int4*)raw = *(const int4*)&p[tid * 8];
    else
        *(int2*)raw = *(const int2*)&p[tid * 4];
    float s = 0.f, ss = 0.f;
#pragma unroll
    for (int i = 0; i < 8; ++i) {
        if (i < E) {
            float f = bf2f(raw[i]);
            s += f;
            ss += f * f;
        }
    }
#pragma unroll
    for (int o = 32; o > 0; o >>= 1) {
        s += __shfl_down(s, o);
        ss += __shfl_down(ss, o);
    }
    __shared__ float sh[8];
    const int wid = tid >> 6;
    if ((tid & 63) == 0) {
        sh[wid] = s;
        sh[wid + 4] = ss;
    }
    __syncthreads();
    s = sh[0] + sh[1] + sh[2] + sh[3];
    ss = sh[4] + sh[5] + sh[6] + sh[7];
    const float inv = 1.0f / (float)D;
    const float mu = s * inv;
    const float var = ss * inv - mu * mu;
    const float rs = rsqrtf(var + 1e-5f);
#pragma unroll
    for (int i = 0; i < 8; ++i) {
        if (i < E) {
            int idx = tid * E + i;
            float f = (bf2f(raw[i]) - mu) * rs * g[idx] + be[idx];
            raw[i] = f2bf(f);
        }
    }
    if (E == 8)
        *(int4*)&p[tid * 8] = *(const int4*)raw;
    else
        *(int2*)&p[tid * 4] = *(const int2*)raw;
}

// ---------------- softmax over rows of S=2048, fp32 in/out + bf16 copy ----------------
__global__ __launch_bounds__(256) void softmax_kernel(float* __restrict__ a,
                                                      u16* __restrict__ ab, int S) {
    const int tid = threadIdx.x;
    float* p = a + (long)blockIdx.x * S;
    __align__(16) float v[8];
    *(float4*)&v[0] = *(const float4*)&p[tid * 8];
    *(float4*)&v[4] = *(const float4*)&p[tid * 8 + 4];
    float mx = v[0];
#pragma unroll
    for (int i = 1; i < 8; ++i) mx = fmaxf(mx, v[i]);
#pragma unroll
    for (int o = 32; o > 0; o >>= 1) mx = fmaxf(mx, __shfl_down(mx, o));
    __shared__ float sh[8];
    const int wid = tid >> 6;
    if ((tid & 63) == 0) sh[wid] = mx;
    __syncthreads();
    mx = fmaxf(fmaxf(sh[0], sh[1]), fmaxf(sh[2], sh[3]));
    float s = 0.f;
#pragma unroll
    for (int i = 0; i < 8; ++i) {
        v[i] = expf(v[i] - mx);
        s += v[i];
    }
#pragma unroll
    for (int o = 32; o > 0; o >>= 1) s += __shfl_down(s, o);
    if ((tid & 63) == 0) sh[4 + wid] = s;
    __syncthreads();
    s = sh[4] + sh[5] + sh[6] + sh[7];
    const float inv = 1.0f / s;
    __align__(16) u16 r[8];
#pragma unroll
    for (int i = 0; i < 8; ++i) {
        v[i] *= inv;
        r[i] = f2bf(v[i]);
    }
    *(float4*)&p[tid * 8] = *(const float4*)&v[0];
    *(float4*)&p[tid * 8 + 4] = *(const float4*)&v[4];
    *(int4*)&ab[(long)blockIdx.x * S + tid * 8] = *(const int4*)r;
}

// ---------------- head: attended(bf16) @ WhT + bh -> gates -> log ----------------
// 128 rows x 64 cols per block, 4 waves (32 rows each), MFMA.
__global__ __launch_bounds__(256) void head_kernel(const u16* __restrict__ A,
                                                   const u16* __restrict__ WhT,
                                                   const float* __restrict__ bh,
                                                   const float* __restrict__ prior,
                                                   const float* __restrict__ ag,
                                                   const float* __restrict__ og,
                                                   float* __restrict__ out) {
    __shared__ __align__(16) u16 As[128 * 64];
    __shared__ __align__(16) u16 Bs[64 * 64];
    const int tid = threadIdx.x;
    const int lane = tid & 63;
    const int wid = tid >> 6;
    const int l15 = lane & 15, lg = lane >> 4;
    const int m0 = blockIdx.x * 128;
    const int srow = tid >> 3, scol = (tid & 7) * 8;
    const u16* pa = A + (long)(m0 + srow) * 1024 + scol;
    const u16* pb = WhT + (long)srow * 1024 + scol;

    f32x4 acc[2][4] = {};
    for (int k0 = 0; k0 < 1024; k0 += 64) {
#pragma unroll
        for (int i = 0; i < 4; ++i) gld16(pa + (long)i * 32 * 1024 + k0, &As[i * 2048 + tid * 8]);
#pragma unroll
        for (int i = 0; i < 2; ++i) gld16(pb + (long)i * 32 * 1024 + k0, &Bs[i * 2048 + tid * 8]);
        __syncthreads();
#pragma unroll
        for (int kk = 0; kk < 2; ++kk) {
            bf16x8 af[2], bfr[4];
#pragma unroll
            for (int m = 0; m < 2; ++m)
                af[m] = *(const bf16x8*)&As[(wid * 32 + m * 16 + l15) * 64 + kk * 32 + lg * 8];
#pragma unroll
            for (int n = 0; n < 4; ++n)
                bfr[n] = *(const bf16x8*)&Bs[(n * 16 + l15) * 64 + kk * 32 + lg * 8];
#pragma unroll
            for (int m = 0; m < 2; ++m)
#pragma unroll
                for (int n = 0; n < 4; ++n)
                    acc[m][n] =
                        __builtin_amdgcn_mfma_f32_16x16x32_bf16(af[m], bfr[n], acc[m][n], 0, 0, 0);
        }
        __syncthreads();
    }

#pragma unroll
    for (int n = 0; n < 4; ++n) {
        const int col = n * 16 + l15;
        const float bhv = bh[col];
        const float agv = ag[col];
        const float ogv = og[col];
#pragma unroll
        for (int m = 0; m < 2; ++m) {
#pragma unroll
            for (int r = 0; r < 4; ++r) {
                const int row = m0 + wid * 32 + m * 16 + lg * 4 + r;
                const float logit = acc[m][n][r] + bhv;
                const int b = row >> 11;
                const float sp = 1.f / (1.f + expf(-prior[b * 64 + col]));
                const float sl = 1.f / (1.f + expf(-logit));
                const float av = fminf(sl, sp) * agv;
                const float ov = fmaxf(sl, sp) * ogv;
                out[(long)row * 64 + col] = logf((av + ov) * 0.5f + 1e-10f);
            }
        }
    }
}

extern "C" void kernel_launch(void* const* d_in, const int* in_sizes, int n_in, void* d_out,
                              int out_size, void* d_ws, size_t ws_size, hipStream_t stream) {
    const float* emb = (const float*)d_in[0];
    const float* prior = (const float*)d_in[1];
    const float* W1 = (const float*)d_in[2];
    const float* b1 = (const float*)d_in[3];
    const float* g1 = (const float*)d_in[4];
    const float* be1 = (const float*)d_in[5];
    const float* W2 = (const float*)d_in[6];
    const float* b2 = (const float*)d_in[7];
    const float* g2 = (const float*)d_in[8];
    const float* be2 = (const float*)d_in[9];
    const float* Wh = (const float*)d_in[10];
    const float* bh = (const float*)d_in[11];
    const float* ag = (const float*)d_in[12];
    const float* og = (const float*)d_in[13];

    const int Bn = 8, S = 2048, DIN = 1024, H1 = 2048, H2 = 1024, Cc = 64;
    const int M = Bn * S;  // 16384

    char* ws = (char*)d_ws;
    size_t off = 0;
    auto alloc = [&](size_t b) {
        size_t o = off;
        off += (b + 255) & ~(size_t)255;
        return o;
    };
    u16* embb = (u16*)(ws + alloc((size_t)M * DIN * 2));
    u16* W1t = (u16*)(ws + alloc((size_t)H1 * DIN * 2));
    u16* W2t = (u16*)(ws + alloc((size_t)H2 * H1 * 2));
    u16* WhT = (u16*)(ws + alloc((size_t)Cc * H2 * 2));
    u16* h = (u16*)(ws + alloc((size_t)M * H1 * 2));
    u16* feat = (u16*)(ws + alloc((size_t)M * H2 * 2));
    u16* featT = (u16*)(ws + alloc((size_t)Bn * H2 * S * 2));
    u16* attnb = (u16*)(ws + alloc((size_t)Bn * S * S * 2));
    u16* attd = (u16*)(ws + alloc((size_t)M * H2 * 2));

    float* out_logits = (float*)d_out;
    float* out_attn = out_logits + (size_t)M * Cc;

    // 1. embeddings -> bf16
    cvt_kernel<<<(int)(((long)M * DIN) / 1024), 256, 0, stream>>>(emb, embb, (long)M * DIN);
    // 2. W1 [DIN][H1] -> W1t [H1][DIN]
    transpose_to_bf16<1><<<dim3(H1 / 32, DIN / 32, 1), 256, 0, stream>>>(W1, W1t, DIN, H1, 0, 0);
    // 3. W2 [H1][H2] -> W2t [H2][H1]
    transpose_to_bf16<1><<<dim3(H2 / 32, H1 / 32, 1), 256, 0, stream>>>(W2, W2t, H1, H2, 0, 0);
    // 3b. Wh [H2][C] -> WhT [C][H2]
    transpose_to_bf16<1><<<dim3(Cc / 32, H2 / 32, 1), 256, 0, stream>>>(Wh, WhT, H2, Cc, 0, 0);
    // 4. h = relu(emb @ W1 + b1)   [M,H1] bf16
    gemm_nt<1><<<dim3(H1 / 128, M / 128, 1), 256, 0, stream>>>(embb, W1t, h, M, H1, DIN, 0, 0, 0,
                                                               b1, 1, 1.0f);
    // 5. LN1 in-place
    ln_kernel<<<M, 256, 0, stream>>>(h, g1, be1, H1);
    // 6. feat = relu(h @ W2 + b2)  [M,H2] bf16
    gemm_nt<1><<<dim3(H2 / 128, M / 128, 1), 256, 0, stream>>>(h, W2t, feat, M, H2, H1, 0, 0, 0,
                                                               b2, 1, 1.0f);
    // 7. LN2 in-place
    ln_kernel<<<M, 256, 0, stream>>>(feat, g2, be2, H2);
    // 8. featT per batch: [S][H2] -> [H2][S]
    transpose_to_bf16<0><<<dim3(H2 / 32, S / 32, Bn), 256, 0, stream>>>(
        feat, featT, S, H2, (long)S * H2, (long)H2 * S);
    // 9. scores = feat @ feat^T / 32  -> d_out attn region (fp32)
    gemm_nt<0><<<dim3(S / 128, S / 128, Bn), 256, 0, stream>>>(feat, feat, out_attn, S, S, H2,
                                                               (long)S * H2, (long)S * H2,
                                                               (long)S * S, nullptr, 0, 0.03125f);
    // 10. softmax rows (writes fp32 output + bf16 copy)
    softmax_kernel<<<M, 256, 0, stream>>>(out_attn, attnb, S);
    // 11. attended = attn @ feat   [S,H2] bf16 per batch
    gemm_nt<1><<<dim3(H2 / 128, S / 128, Bn), 256, 0, stream>>>(attnb, featT, attd, S, H2, S,
                                                                (long)S * S, (long)H2 * S,
                                                                (long)S * H2, nullptr, 0, 1.0f);
    // 12. head + logic gates + log (MFMA)
    head_kernel<<<M / 128, 256, 0, stream>>>(attd, WhT, bh, prior, ag, og, out_logits);
}

// Round 3
// 615.398 us; speedup vs baseline: 1.2757x; 1.1825x over previous
//
#include <hip/hip_runtime.h>

typedef unsigned short u16;
typedef __bf16 bf16x8 __attribute__((ext_vector_type(8)));
typedef float f32x4 __attribute__((ext_vector_type(4)));

__device__ __forceinline__ u16 f2bf(float f) {
    unsigned u = __float_as_uint(f);
    u = (u + 0x7FFFu + ((u >> 16) & 1u)) >> 16;
    return (u16)u;
}
__device__ __forceinline__ float bf2f(u16 h) {
    return __uint_as_float(((unsigned)h) << 16);
}

// async global -> LDS, 16B per lane
__device__ __forceinline__ void gld16(const u16* g, u16* l) {
    __builtin_amdgcn_global_load_lds((const __attribute__((address_space(1))) void*)g,
                                     (__attribute__((address_space(3))) void*)l, 16, 0, 0);
}

// ---------------- convert fp32 -> bf16 (flat) ----------------
__global__ __launch_bounds__(256) void cvt_kernel(const float* __restrict__ in,
                                                  u16* __restrict__ out, long n) {
    long i = ((long)blockIdx.x * blockDim.x + threadIdx.x) * 4;
    if (i + 3 < n) {
        float4 v = *(const float4*)&in[i];
        __align__(8) u16 r[4] = {f2bf(v.x), f2bf(v.y), f2bf(v.z), f2bf(v.w)};
        *(int2*)&out[i] = *(const int2*)r;
    }
}

// ---------------- transpose (+convert) -> bf16 ----------------
template <int INF32>
__global__ __launch_bounds__(256) void transpose_to_bf16(const void* __restrict__ in,
                                                         u16* __restrict__ out, int R, int C,
                                                         long inB, long outB) {
    __shared__ float tile[32][33];
    const long zi = (long)blockIdx.z * inB;
    const long zo = (long)blockIdx.z * outB;
    const int c0 = blockIdx.x * 32, r0 = blockIdx.y * 32;
    const int tx = threadIdx.x & 31;
    const int ty = threadIdx.x >> 5;  // 0..7
#pragma unroll
    for (int i = 0; i < 32; i += 8) {
        long idx = zi + (long)(r0 + ty + i) * C + c0 + tx;
        float v = INF32 ? ((const float*)in)[idx] : bf2f(((const u16*)in)[idx]);
        tile[ty + i][tx] = v;
    }
    __syncthreads();
#pragma unroll
    for (int i = 0; i < 32; i += 8) {
        out[zo + (long)(c0 + ty + i) * R + r0 + tx] = f2bf(tile[tx][ty + i]);
    }
}

// ---------------- generic NT bf16 MFMA GEMM (m97 structure + XCD swizzle + symm) --------
// C[M,N] = scale * (A[M,K] @ B[N,K]^T) + bias, optional relu.
// symm: M==N, A==B per batch; compute upper triangle of blocks, mirror-write.
template <int OUTBF>
__global__ __launch_bounds__(256) void gemm_nt(const u16* __restrict__ A,
                                               const u16* __restrict__ Bm,
                                               void* __restrict__ Cout, int M, int N, int K,
                                               long sA, long sB, long sC,
                                               const float* __restrict__ bias, int relu,
                                               float scale, int symm) {
    // ---- bijective XCD swizzle (m204) over the x*y grid ----
    const int nx = gridDim.x;
    const int nwg = nx * gridDim.y;
    const int orig = blockIdx.y * nx + blockIdx.x;
    const int q = nwg >> 3, r = nwg & 7, xcd = orig & 7, o8 = orig >> 3;
    const int wgid = (xcd < r ? xcd * (q + 1) : r * (q + 1) + (xcd - r) * q) + o8;
    const int bx = wgid % nx, by = wgid / nx;
    if (symm && by > bx) return;

    __shared__ __align__(16) u16 As[128 * 64];
    __shared__ __align__(16) u16 Bs[128 * 64];
    const int tid = threadIdx.x;
    const int lane = tid & 63;
    const int wid = tid >> 6;
    const int wr = wid >> 1, wc = wid & 1;
    const int l15 = lane & 15, lg = lane >> 4;
    const long zA = (long)blockIdx.z * sA;
    const long zB = (long)blockIdx.z * sB;
    const long zC = (long)blockIdx.z * sC;
    const int m0 = by * 128, n0 = bx * 128;

    f32x4 acc[4][4] = {};

    const int srow = tid >> 3;       // 0..31
    const int scol = (tid & 7) * 8;  // shorts
    const u16* pa = A + zA + (long)(m0 + srow) * K + scol;
    const u16* pb = Bm + zB + (long)(n0 + srow) * K + scol;

    for (int k0 = 0; k0 < K; k0 += 64) {
#pragma unroll
        for (int i = 0; i < 4; ++i) gld16(pa + (long)i * 32 * K + k0, &As[i * 2048 + tid * 8]);
#pragma unroll
        for (int i = 0; i < 4; ++i) gld16(pb + (long)i * 32 * K + k0, &Bs[i * 2048 + tid * 8]);
        __syncthreads();
#pragma unroll
        for (int kk = 0; kk < 2; ++kk) {
            bf16x8 af[4], bfr[4];
#pragma unroll
            for (int m = 0; m < 4; ++m)
                af[m] = *(const bf16x8*)&As[(wr * 64 + m * 16 + l15) * 64 + kk * 32 + lg * 8];
#pragma unroll
            for (int n = 0; n < 4; ++n)
                bfr[n] = *(const bf16x8*)&Bs[(wc * 64 + n * 16 + l15) * 64 + kk * 32 + lg * 8];
#pragma unroll
            for (int m = 0; m < 4; ++m)
#pragma unroll
                for (int n = 0; n < 4; ++n)
                    acc[m][n] =
                        __builtin_amdgcn_mfma_f32_16x16x32_bf16(af[m], bfr[n], acc[m][n], 0, 0, 0);
        }
        __syncthreads();
    }

#pragma unroll
    for (int n = 0; n < 4; ++n) {
        const int col = n0 + wc * 64 + n * 16 + l15;
        const float bv = bias ? bias[col] : 0.0f;
#pragma unroll
        for (int m = 0; m < 4; ++m) {
            const int rowb = m0 + wr * 64 + m * 16 + lg * 4;
            float v[4];
#pragma unroll
            for (int r = 0; r < 4; ++r) {
                float f = acc[m][n][r] * scale + bv;
                if (relu) f = fmaxf(f, 0.0f);
                v[r] = f;
                if (OUTBF)
                    ((u16*)Cout)[zC + (long)(rowb + r) * N + col] = f2bf(f);
                else
                    ((float*)Cout)[zC + (long)(rowb + r) * N + col] = f;
            }
            if (!OUTBF && symm && bx > by) {
                float4 tv = make_float4(v[0], v[1], v[2], v[3]);
                *(float4*)&((float*)Cout)[zC + (long)col * N + rowb] = tv;
            }
        }
    }
}

// ---------------- LayerNorm, wave-per-row (bf16 in/out, in-place) ----------------
// CH = D/512 chunks; each lane handles CH*8 elements.
template <int CH>
__global__ __launch_bounds__(256) void ln_wave(u16* __restrict__ x, const float* __restrict__ g,
                                               const float* __restrict__ be) {
    const int lane = threadIdx.x & 63;
    const int wid = threadIdx.x >> 6;
    const long row = (long)blockIdx.x * 4 + wid;
    u16* p = x + row * (CH * 512);
    __align__(16) u16 raw[CH][8];
    float s = 0.f, ss = 0.f;
#pragma unroll
    for (int c = 0; c < CH; ++c) {
        *(int4*)raw[c] = *(const int4*)&p[(c * 64 + lane) * 8];
#pragma unroll
        for (int j = 0; j < 8; ++j) {
            float f = bf2f(raw[c][j]);
            s += f;
            ss += f * f;
        }
    }
#pragma unroll
    for (int o = 1; o < 64; o <<= 1) {
        s += __shfl_xor(s, o);
        ss += __shfl_xor(ss, o);
    }
    const float inv = 1.0f / (float)(CH * 512);
    const float mu = s * inv;
    const float var = ss * inv - mu * mu;
    const float rs = rsqrtf(var + 1e-5f);
#pragma unroll
    for (int c = 0; c < CH; ++c) {
        const int base = (c * 64 + lane) * 8;
        float4 g0 = *(const float4*)&g[base];
        float4 g1 = *(const float4*)&g[base + 4];
        float4 b0 = *(const float4*)&be[base];
        float4 b1 = *(const float4*)&be[base + 4];
        float gv[8] = {g0.x, g0.y, g0.z, g0.w, g1.x, g1.y, g1.z, g1.w};
        float bv[8] = {b0.x, b0.y, b0.z, b0.w, b1.x, b1.y, b1.z, b1.w};
#pragma unroll
        for (int j = 0; j < 8; ++j)
            raw[c][j] = f2bf((bf2f(raw[c][j]) - mu) * rs * gv[j] + bv[j]);
        *(int4*)&p[base] = *(const int4*)raw[c];
    }
}

// ---------------- softmax, wave-per-row over S=2048, fp32 in/out + bf16 copy ----------
__global__ __launch_bounds__(256) void softmax_wave(float* __restrict__ a,
                                                    u16* __restrict__ ab) {
    const int lane = threadIdx.x & 63;
    const int wid = threadIdx.x >> 6;
    const long row = (long)blockIdx.x * 4 + wid;
    float* p = a + row * 2048;
    float v[4][8];
    float mx = -3.4e38f;
#pragma unroll
    for (int c = 0; c < 4; ++c) {
        const int base = (c * 64 + lane) * 8;
        *(float4*)&v[c][0] = *(const float4*)&p[base];
        *(float4*)&v[c][4] = *(const float4*)&p[base + 4];
#pragma unroll
        for (int j = 0; j < 8; ++j) mx = fmaxf(mx, v[c][j]);
    }
#pragma unroll
    for (int o = 1; o < 64; o <<= 1) mx = fmaxf(mx, __shfl_xor(mx, o));
    float s = 0.f;
#pragma unroll
    for (int c = 0; c < 4; ++c)
#pragma unroll
        for (int j = 0; j < 8; ++j) {
            v[c][j] = expf(v[c][j] - mx);
            s += v[c][j];
        }
#pragma unroll
    for (int o = 1; o < 64; o <<= 1) s += __shfl_xor(s, o);
    const float inv = 1.0f / s;
#pragma unroll
    for (int c = 0; c < 4; ++c) {
        const int base = (c * 64 + lane) * 8;
        __align__(16) u16 rb[8];
#pragma unroll
        for (int j = 0; j < 8; ++j) {
            v[c][j] *= inv;
            rb[j] = f2bf(v[c][j]);
        }
        *(float4*)&p[base] = *(const float4*)&v[c][0];
        *(float4*)&p[base + 4] = *(const float4*)&v[c][4];
        *(int4*)&ab[row * 2048 + base] = *(const int4*)rb;
    }
}

// ---------------- head: attended(bf16) @ WhT + bh -> gates -> log ----------------
__global__ __launch_bounds__(256) void head_kernel(const u16* __restrict__ A,
                                                   const u16* __restrict__ WhT,
                                                   const float* __restrict__ bh,
                                                   const float* __restrict__ prior,
                                                   const float* __restrict__ ag,
                                                   const float* __restrict__ og,
                                                   float* __restrict__ out) {
    __shared__ __align__(16) u16 As[128 * 64];
    __shared__ __align__(16) u16 Bs[64 * 64];
    const int tid = threadIdx.x;
    const int lane = tid & 63;
    const int wid = tid >> 6;
    const int l15 = lane & 15, lg = lane >> 4;
    const int m0 = blockIdx.x * 128;
    const int srow = tid >> 3, scol = (tid & 7) * 8;
    const u16* pa = A + (long)(m0 + srow) * 1024 + scol;
    const u16* pb = WhT + (long)srow * 1024 + scol;

    f32x4 acc[2][4] = {};
    for (int k0 = 0; k0 < 1024; k0 += 64) {
#pragma unroll
        for (int i = 0; i < 4; ++i) gld16(pa + (long)i * 32 * 1024 + k0, &As[i * 2048 + tid * 8]);
#pragma unroll
        for (int i = 0; i < 2; ++i) gld16(pb + (long)i * 32 * 1024 + k0, &Bs[i * 2048 + tid * 8]);
        __syncthreads();
#pragma unroll
        for (int kk = 0; kk < 2; ++kk) {
            bf16x8 af[2], bfr[4];
#pragma unroll
            for (int m = 0; m < 2; ++m)
                af[m] = *(const bf16x8*)&As[(wid * 32 + m * 16 + l15) * 64 + kk * 32 + lg * 8];
#pragma unroll
            for (int n = 0; n < 4; ++n)
                bfr[n] = *(const bf16x8*)&Bs[(n * 16 + l15) * 64 + kk * 32 + lg * 8];
#pragma unroll
            for (int m = 0; m < 2; ++m)
#pragma unroll
                for (int n = 0; n < 4; ++n)
                    acc[m][n] =
                        __builtin_amdgcn_mfma_f32_16x16x32_bf16(af[m], bfr[n], acc[m][n], 0, 0, 0);
        }
        __syncthreads();
    }

#pragma unroll
    for (int n = 0; n < 4; ++n) {
        const int col = n * 16 + l15;
        const float bhv = bh[col];
        const float agv = ag[col];
        const float ogv = og[col];
#pragma unroll
        for (int m = 0; m < 2; ++m) {
#pragma unroll
            for (int r = 0; r < 4; ++r) {
                const int row = m0 + wid * 32 + m * 16 + lg * 4 + r;
                const float logit = acc[m][n][r] + bhv;
                const int b = row >> 11;
                const float sp = 1.f / (1.f + expf(-prior[b * 64 + col]));
                const float sl = 1.f / (1.f + expf(-logit));
                const float av = fminf(sl, sp) * agv;
                const float ov = fmaxf(sl, sp) * ogv;
                out[(long)row * 64 + col] = logf((av + ov) * 0.5f + 1e-10f);
            }
        }
    }
}

extern "C" void kernel_launch(void* const* d_in, const int* in_sizes, int n_in, void* d_out,
                              int out_size, void* d_ws, size_t ws_size, hipStream_t stream) {
    const float* emb = (const float*)d_in[0];
    const float* prior = (const float*)d_in[1];
    const float* W1 = (const float*)d_in[2];
    const float* b1 = (const float*)d_in[3];
    const float* g1 = (const float*)d_in[4];
    const float* be1 = (const float*)d_in[5];
    const float* W2 = (const float*)d_in[6];
    const float* b2 = (const float*)d_in[7];
    const float* g2 = (const float*)d_in[8];
    const float* be2 = (const float*)d_in[9];
    const float* Wh = (const float*)d_in[10];
    const float* bh = (const float*)d_in[11];
    const float* ag = (const float*)d_in[12];
    const float* og = (const float*)d_in[13];

    const int Bn = 8, S = 2048, DIN = 1024, H1 = 2048, H2 = 1024, Cc = 64;
    const int M = Bn * S;  // 16384

    char* ws = (char*)d_ws;
    size_t off = 0;
    auto alloc = [&](size_t b) {
        size_t o = off;
        off += (b + 255) & ~(size_t)255;
        return o;
    };
    u16* embb = (u16*)(ws + alloc((size_t)M * DIN * 2));
    u16* W1t = (u16*)(ws + alloc((size_t)H1 * DIN * 2));
    u16* W2t = (u16*)(ws + alloc((size_t)H2 * H1 * 2));
    u16* WhT = (u16*)(ws + alloc((size_t)Cc * H2 * 2));
    u16* h = (u16*)(ws + alloc((size_t)M * H1 * 2));
    u16* feat = (u16*)(ws + alloc((size_t)M * H2 * 2));
    u16* featT = (u16*)(ws + alloc((size_t)Bn * H2 * S * 2));
    u16* attnb = (u16*)(ws + alloc((size_t)Bn * S * S * 2));
    u16* attd = (u16*)(ws + alloc((size_t)M * H2 * 2));

    float* out_logits = (float*)d_out;
    float* out_attn = out_logits + (size_t)M * Cc;

    // 1. embeddings -> bf16
    cvt_kernel<<<(int)(((long)M * DIN) / 1024), 256, 0, stream>>>(emb, embb, (long)M * DIN);
    // 2. W1 [DIN][H1] -> W1t [H1][DIN]
    transpose_to_bf16<1><<<dim3(H1 / 32, DIN / 32, 1), 256, 0, stream>>>(W1, W1t, DIN, H1, 0, 0);
    // 3. W2 [H1][H2] -> W2t [H2][H1]
    transpose_to_bf16<1><<<dim3(H2 / 32, H1 / 32, 1), 256, 0, stream>>>(W2, W2t, H1, H2, 0, 0);
    // 3b. Wh [H2][C] -> WhT [C][H2]
    transpose_to_bf16<1><<<dim3(Cc / 32, H2 / 32, 1), 256, 0, stream>>>(Wh, WhT, H2, Cc, 0, 0);
    // 4. h = relu(emb @ W1 + b1)   [M,H1] bf16
    gemm_nt<1><<<dim3(H1 / 128, M / 128, 1), 256, 0, stream>>>(embb, W1t, h, M, H1, DIN, 0, 0, 0,
                                                               b1, 1, 1.0f, 0);
    // 5. LN1 (wave-per-row)
    ln_wave<4><<<M / 4, 256, 0, stream>>>(h, g1, be1);
    // 6. feat = relu(h @ W2 + b2)  [M,H2] bf16
    gemm_nt<1><<<dim3(H2 / 128, M / 128, 1), 256, 0, stream>>>(h, W2t, feat, M, H2, H1, 0, 0, 0,
                                                               b2, 1, 1.0f, 0);
    // 7. LN2
    ln_wave<2><<<M / 4, 256, 0, stream>>>(feat, g2, be2);
    // 8. featT per batch: [S][H2] -> [H2][S]
    transpose_to_bf16<0><<<dim3(H2 / 32, S / 32, Bn), 256, 0, stream>>>(
        feat, featT, S, H2, (long)S * H2, (long)H2 * S);
    // 9. scores = feat @ feat^T / 32  -> d_out attn region (fp32), symmetric
    gemm_nt<0><<<dim3(S / 128, S / 128, Bn), 256, 0, stream>>>(feat, feat, out_attn, S, S, H2,
                                                               (long)S * H2, (long)S * H2,
                                                               (long)S * S, nullptr, 0, 0.03125f,
                                                               1);
    // 10. softmax rows (fp32 in/out + bf16 copy)
    softmax_wave<<<M / 4, 256, 0, stream>>>(out_attn, attnb);
    // 11. attended = attn @ feat   [S,H2] bf16 per batch
    gemm_nt<1><<<dim3(H2 / 128, S / 128, Bn), 256, 0, stream>>>(attnb, featT, attd, S, H2, S,
                                                                (long)S * S, (long)H2 * S,
                                                                (long)S * H2, nullptr, 0, 1.0f,
                                                                0);
    // 12. head + logic gates + log (MFMA)
    head_kernel<<<M / 128, 256, 0, stream>>>(attd, WhT, bh, prior, ag, og, out_logits);
}

// Round 5
// 563.730 us; speedup vs baseline: 1.3926x; 1.0917x over previous
//
#include <hip/hip_runtime.h>

typedef unsigned short u16;
typedef __bf16 bf16x8 __attribute__((ext_vector_type(8)));
typedef float f32x4 __attribute__((ext_vector_type(4)));

__device__ __forceinline__ u16 f2bf(float f) {
    unsigned u = __float_as_uint(f);
    u = (u + 0x7FFFu + ((u >> 16) & 1u)) >> 16;
    return (u16)u;
}
__device__ __forceinline__ float bf2f(u16 h) {
    return __uint_as_float(((unsigned)h) << 16);
}

// async global -> LDS, 16B per lane
__device__ __forceinline__ void gld16(const u16* g, u16* l) {
    __builtin_amdgcn_global_load_lds((const __attribute__((address_space(1))) void*)g,
                                     (__attribute__((address_space(3))) void*)l, 16, 0, 0);
}

// ---------------- convert fp32 -> bf16 (flat) ----------------
__global__ __launch_bounds__(256) void cvt_kernel(const float* __restrict__ in,
                                                  u16* __restrict__ out, long n) {
    long i = ((long)blockIdx.x * blockDim.x + threadIdx.x) * 4;
    if (i + 3 < n) {
        float4 v = *(const float4*)&in[i];
        __align__(8) u16 r[4] = {f2bf(v.x), f2bf(v.y), f2bf(v.z), f2bf(v.w)};
        *(int2*)&out[i] = *(const int2*)r;
    }
}

// ---------------- transpose (+convert) -> bf16 ----------------
template <int INF32>
__global__ __launch_bounds__(256) void transpose_to_bf16(const void* __restrict__ in,
                                                         u16* __restrict__ out, int R, int C,
                                                         long inB, long outB) {
    __shared__ float tile[32][33];
    const long zi = (long)blockIdx.z * inB;
    const long zo = (long)blockIdx.z * outB;
    const int c0 = blockIdx.x * 32, r0 = blockIdx.y * 32;
    const int tx = threadIdx.x & 31;
    const int ty = threadIdx.x >> 5;  // 0..7
#pragma unroll
    for (int i = 0; i < 32; i += 8) {
        long idx = zi + (long)(r0 + ty + i) * C + c0 + tx;
        float v = INF32 ? ((const float*)in)[idx] : bf2f(((const u16*)in)[idx]);
        tile[ty + i][tx] = v;
    }
    __syncthreads();
#pragma unroll
    for (int i = 0; i < 32; i += 8) {
        out[zo + (long)(c0 + ty + i) * R + r0 + tx] = f2bf(tile[tx][ty + i]);
    }
}

// ---------------- generic NT bf16 MFMA GEMM (m97 structure + XCD swizzle + symm) --------
// C[M,N] = scale * (A[M,K] @ B[N,K]^T) + bias, optional relu.
// symm: M==N, A==B per batch; grid.x = Bn * NB*(NB+1)/2 flat; exact balanced
//       triangle enumeration (batch == XCD); mirror-writes transposed tile.
template <int OUTBF>
__global__ __launch_bounds__(256) void gemm_nt(const u16* __restrict__ A,
                                               const u16* __restrict__ Bm,
                                               void* __restrict__ Cout, int M, int N, int K,
                                               long sA, long sB, long sC,
                                               const float* __restrict__ bias, int relu,
                                               float scale, int symm) {
    int bx, by, zz;
    if (symm) {
        // grid.x = Bn * nTri (divisible by 8); wgid/nTri = batch = XCD
        const int q = gridDim.x >> 3;
        const int orig = blockIdx.x;
        const int wgid = (orig & 7) * q + (orig >> 3);
        const int NB = N >> 7;
        const int nTri = (NB * (NB + 1)) >> 1;
        zz = wgid / nTri;
        int t = wgid - zz * nTri;
        by = 0;
        int rem = NB;
        while (t >= rem) {
            t -= rem;
            --rem;
            ++by;
        }
        bx = by + t;
    } else {
        const int nx = gridDim.x;
        const int nwg = nx * gridDim.y;
        const int orig = blockIdx.y * nx + blockIdx.x;
        const int q = nwg >> 3, r = nwg & 7, xcd = orig & 7, o8 = orig >> 3;
        const int wgid = (xcd < r ? xcd * (q + 1) : r * (q + 1) + (xcd - r) * q) + o8;
        bx = wgid % nx;
        by = wgid / nx;
        zz = blockIdx.z;
    }

    __shared__ __align__(16) u16 As[128 * 64];
    __shared__ __align__(16) u16 Bs[128 * 64];
    const int tid = threadIdx.x;
    const int lane = tid & 63;
    const int wid = tid >> 6;
    const int wr = wid >> 1, wc = wid & 1;
    const int l15 = lane & 15, lg = lane >> 4;
    const long zA = (long)zz * sA;
    const long zB = (long)zz * sB;
    const long zC = (long)zz * sC;
    const int m0 = by * 128, n0 = bx * 128;

    f32x4 acc[4][4] = {};

    const int srow = tid >> 3;       // 0..31
    const int scol = (tid & 7) * 8;  // shorts
    const u16* pa = A + zA + (long)(m0 + srow) * K + scol;
    const u16* pb = Bm + zB + (long)(n0 + srow) * K + scol;

    for (int k0 = 0; k0 < K; k0 += 64) {
#pragma unroll
        for (int i = 0; i < 4; ++i) gld16(pa + (long)i * 32 * K + k0, &As[i * 2048 + tid * 8]);
#pragma unroll
        for (int i = 0; i < 4; ++i) gld16(pb + (long)i * 32 * K + k0, &Bs[i * 2048 + tid * 8]);
        __syncthreads();
#pragma unroll
        for (int kk = 0; kk < 2; ++kk) {
            bf16x8 af[4], bfr[4];
#pragma unroll
            for (int m = 0; m < 4; ++m)
                af[m] = *(const bf16x8*)&As[(wr * 64 + m * 16 + l15) * 64 + kk * 32 + lg * 8];
#pragma unroll
            for (int n = 0; n < 4; ++n)
                bfr[n] = *(const bf16x8*)&Bs[(wc * 64 + n * 16 + l15) * 64 + kk * 32 + lg * 8];
#pragma unroll
            for (int m = 0; m < 4; ++m)
#pragma unroll
                for (int n = 0; n < 4; ++n)
                    acc[m][n] =
                        __builtin_amdgcn_mfma_f32_16x16x32_bf16(af[m], bfr[n], acc[m][n], 0, 0, 0);
        }
        __syncthreads();
    }

#pragma unroll
    for (int n = 0; n < 4; ++n) {
        const int col = n0 + wc * 64 + n * 16 + l15;
        const float bv = bias ? bias[col] : 0.0f;
#pragma unroll
        for (int m = 0; m < 4; ++m) {
            const int rowb = m0 + wr * 64 + m * 16 + lg * 4;
            float v[4];
#pragma unroll
            for (int r = 0; r < 4; ++r) {
                float f = acc[m][n][r] * scale + bv;
                if (relu) f = fmaxf(f, 0.0f);
                v[r] = f;
                if (OUTBF)
                    ((u16*)Cout)[zC + (long)(rowb + r) * N + col] = f2bf(f);
                else
                    ((float*)Cout)[zC + (long)(rowb + r) * N + col] = f;
            }
            if (!OUTBF && symm && bx > by) {
                float4 tv = make_float4(v[0], v[1], v[2], v[3]);
                *(float4*)&((float*)Cout)[zC + (long)col * N + rowb] = tv;
            }
        }
    }
}

// ---------------- LayerNorm, wave-per-row (bf16 in/out, in-place) ----------------
template <int CH>
__global__ __launch_bounds__(256) void ln_wave(u16* __restrict__ x, const float* __restrict__ g,
                                               const float* __restrict__ be) {
    const int lane = threadIdx.x & 63;
    const int wid = threadIdx.x >> 6;
    const long row = (long)blockIdx.x * 4 + wid;
    u16* p = x + row * (CH * 512);
    __align__(16) u16 raw[CH][8];
    float s = 0.f, ss = 0.f;
#pragma unroll
    for (int c = 0; c < CH; ++c) {
        *(int4*)raw[c] = *(const int4*)&p[(c * 64 + lane) * 8];
#pragma unroll
        for (int j = 0; j < 8; ++j) {
            float f = bf2f(raw[c][j]);
            s += f;
            ss += f * f;
        }
    }
#pragma unroll
    for (int o = 1; o < 64; o <<= 1) {
        s += __shfl_xor(s, o);
        ss += __shfl_xor(ss, o);
    }
    const float inv = 1.0f / (float)(CH * 512);
    const float mu = s * inv;
    const float var = ss * inv - mu * mu;
    const float rs = rsqrtf(var + 1e-5f);
#pragma unroll
    for (int c = 0; c < CH; ++c) {
        const int base = (c * 64 + lane) * 8;
        float4 g0 = *(const float4*)&g[base];
        float4 g1 = *(const float4*)&g[base + 4];
        float4 b0 = *(const float4*)&be[base];
        float4 b1 = *(const float4*)&be[base + 4];
        float gv[8] = {g0.x, g0.y, g0.z, g0.w, g1.x, g1.y, g1.z, g1.w};
        float bv[8] = {b0.x, b0.y, b0.z, b0.w, b1.x, b1.y, b1.z, b1.w};
#pragma unroll
        for (int j = 0; j < 8; ++j)
            raw[c][j] = f2bf((bf2f(raw[c][j]) - mu) * rs * gv[j] + bv[j]);
        *(int4*)&p[base] = *(const int4*)raw[c];
    }
}

// ---------------- softmax, wave-per-row over S=2048, fp32 in/out + bf16 copy ----------
__global__ __launch_bounds__(256) void softmax_wave(float* __restrict__ a,
                                                    u16* __restrict__ ab) {
    const int lane = threadIdx.x & 63;
    const int wid = threadIdx.x >> 6;
    const long row = (long)blockIdx.x * 4 + wid;
    float* p = a + row * 2048;
    float v[4][8];
    float mx = -3.4e38f;
#pragma unroll
    for (int c = 0; c < 4; ++c) {
        const int base = (c * 64 + lane) * 8;
        *(float4*)&v[c][0] = *(const float4*)&p[base];
        *(float4*)&v[c][4] = *(const float4*)&p[base + 4];
#pragma unroll
        for (int j = 0; j < 8; ++j) mx = fmaxf(mx, v[c][j]);
    }
#pragma unroll
    for (int o = 1; o < 64; o <<= 1) mx = fmaxf(mx, __shfl_xor(mx, o));
    float s = 0.f;
#pragma unroll
    for (int c = 0; c < 4; ++c)
#pragma unroll
        for (int j = 0; j < 8; ++j) {
            v[c][j] = expf(v[c][j] - mx);
            s += v[c][j];
        }
#pragma unroll
    for (int o = 1; o < 64; o <<= 1) s += __shfl_xor(s, o);
    const float inv = 1.0f / s;
#pragma unroll
    for (int c = 0; c < 4; ++c) {
        const int base = (c * 64 + lane) * 8;
        __align__(16) u16 rb[8];
#pragma unroll
        for (int j = 0; j < 8; ++j) {
            v[c][j] *= inv;
            rb[j] = f2bf(v[c][j]);
        }
        *(float4*)&p[base] = *(const float4*)&v[c][0];
        *(float4*)&p[base + 4] = *(const float4*)&v[c][4];
        *(int4*)&ab[row * 2048 + base] = *(const int4*)rb;
    }
}

// ---------------- head: attended(bf16) @ WhT + bh -> gates -> log ----------------
__global__ __launch_bounds__(256) void head_kernel(const u16* __restrict__ A,
                                                   const u16* __restrict__ WhT,
                                                   const float* __restrict__ bh,
                                                   const float* __restrict__ prior,
                                                   const float* __restrict__ ag,
                                                   const float* __restrict__ og,
                                                   float* __restrict__ out) {
    __shared__ __align__(16) u16 As[128 * 64];
    __shared__ __align__(16) u16 Bs[64 * 64];
    const int tid = threadIdx.x;
    const int lane = tid & 63;
    const int wid = tid >> 6;
    const int l15 = lane & 15, lg = lane >> 4;
    const int m0 = blockIdx.x * 128;
    const int srow = tid >> 3, scol = (tid & 7) * 8;
    const u16* pa = A + (long)(m0 + srow) * 1024 + scol;
    const u16* pb = WhT + (long)srow * 1024 + scol;

    f32x4 acc[2][4] = {};
    for (int k0 = 0; k0 < 1024; k0 += 64) {
#pragma unroll
        for (int i = 0; i < 4; ++i) gld16(pa + (long)i * 32 * 1024 + k0, &As[i * 2048 + tid * 8]);
#pragma unroll
        for (int i = 0; i < 2; ++i) gld16(pb + (long)i * 32 * 1024 + k0, &Bs[i * 2048 + tid * 8]);
        __syncthreads();
#pragma unroll
        for (int kk = 0; kk < 2; ++kk) {
            bf16x8 af[2], bfr[4];
#pragma unroll
            for (int m = 0; m < 2; ++m)
                af[m] = *(const bf16x8*)&As[(wid * 32 + m * 16 + l15) * 64 + kk * 32 + lg * 8];
#pragma unroll
            for (int n = 0; n < 4; ++n)
                bfr[n] = *(const bf16x8*)&Bs[(n * 16 + l15) * 64 + kk * 32 + lg * 8];
#pragma unroll
            for (int m = 0; m < 2; ++m)
#pragma unroll
                for (int n = 0; n < 4; ++n)
                    acc[m][n] =
                        __builtin_amdgcn_mfma_f32_16x16x32_bf16(af[m], bfr[n], acc[m][n], 0, 0, 0);
        }
        __syncthreads();
    }

#pragma unroll
    for (int n = 0; n < 4; ++n) {
        const int col = n * 16 + l15;
        const float bhv = bh[col];
        const float agv = ag[col];
        const float ogv = og[col];
#pragma unroll
        for (int m = 0; m < 2; ++m) {
#pragma unroll
            for (int r = 0; r < 4; ++r) {
                const int row = m0 + wid * 32 + m * 16 + lg * 4 + r;
                const float logit = acc[m][n][r] + bhv;
                const int b = row >> 11;
                const float sp = 1.f / (1.f + expf(-prior[b * 64 + col]));
                const float sl = 1.f / (1.f + expf(-logit));
                const float av = fminf(sl, sp) * agv;
                const float ov = fmaxf(sl, sp) * ogv;
                out[(long)row * 64 + col] = logf((av + ov) * 0.5f + 1e-10f);
            }
        }
    }
}

extern "C" void kernel_launch(void* const* d_in, const int* in_sizes, int n_in, void* d_out,
                              int out_size, void* d_ws, size_t ws_size, hipStream_t stream) {
    const float* emb = (const float*)d_in[0];
    const float* prior = (const float*)d_in[1];
    const float* W1 = (const float*)d_in[2];
    const float* b1 = (const float*)d_in[3];
    const float* g1 = (const float*)d_in[4];
    const float* be1 = (const float*)d_in[5];
    const float* W2 = (const float*)d_in[6];
    const float* b2 = (const float*)d_in[7];
    const float* g2 = (const float*)d_in[8];
    const float* be2 = (const float*)d_in[9];
    const float* Wh = (const float*)d_in[10];
    const float* bh = (const float*)d_in[11];
    const float* ag = (const float*)d_in[12];
    const float* og = (const float*)d_in[13];

    const int Bn = 8, S = 2048, DIN = 1024, H1 = 2048, H2 = 1024, Cc = 64;
    const int M = Bn * S;  // 16384

    char* ws = (char*)d_ws;
    size_t off = 0;
    auto alloc = [&](size_t b) {
        size_t o = off;
        off += (b + 255) & ~(size_t)255;
        return o;
    };
    // Live-range-shared regions (peak ~136 MB, well under the proven 277 MB):
    //   R0 (64MB): h (steps 4-6)      then attnb (steps 10-11)
    //   R1 (32MB): embb (steps 1-4)   then featT (steps 8-11)
    //   R2 (32MB): feat (steps 6-9)   then attd (steps 11-12)
    char* R0 = ws + alloc((size_t)M * H1 * 2);       // 64MB
    char* R1 = ws + alloc((size_t)M * DIN * 2);      // 32MB
    char* R2 = ws + alloc((size_t)M * H2 * 2);       // 32MB
    u16* W1t = (u16*)(ws + alloc((size_t)H1 * DIN * 2));
    u16* W2t = (u16*)(ws + alloc((size_t)H2 * H1 * 2));
    u16* WhT = (u16*)(ws + alloc((size_t)Cc * H2 * 2));

    u16* h = (u16*)R0;
    u16* attnb = (u16*)R0;
    u16* embb = (u16*)R1;
    u16* featT = (u16*)R1;
    u16* feat = (u16*)R2;
    u16* attd = (u16*)R2;

    float* out_logits = (float*)d_out;
    float* out_attn = out_logits + (size_t)M * Cc;

    // 1. embeddings -> bf16
    cvt_kernel<<<(int)(((long)M * DIN) / 1024), 256, 0, stream>>>(emb, embb, (long)M * DIN);
    // 2. W1 [DIN][H1] -> W1t [H1][DIN]
    transpose_to_bf16<1><<<dim3(H1 / 32, DIN / 32, 1), 256, 0, stream>>>(W1, W1t, DIN, H1, 0, 0);
    // 3. W2 [H1][H2] -> W2t [H2][H1]
    transpose_to_bf16<1><<<dim3(H2 / 32, H1 / 32, 1), 256, 0, stream>>>(W2, W2t, H1, H2, 0, 0);
    // 3b. Wh [H2][C] -> WhT [C][H2]
    transpose_to_bf16<1><<<dim3(Cc / 32, H2 / 32, 1), 256, 0, stream>>>(Wh, WhT, H2, Cc, 0, 0);
    // 4. h = relu(emb @ W1 + b1)   [M,H1] bf16
    gemm_nt<1><<<dim3(H1 / 128, M / 128, 1), 256, 0, stream>>>(embb, W1t, h, M, H1, DIN, 0, 0, 0,
                                                               b1, 1, 1.0f, 0);
    // 5. LN1 (wave-per-row)
    ln_wave<4><<<M / 4, 256, 0, stream>>>(h, g1, be1);
    // 6. feat = relu(h @ W2 + b2)  [M,H2] bf16
    gemm_nt<1><<<dim3(H2 / 128, M / 128, 1), 256, 0, stream>>>(h, W2t, feat, M, H2, H1, 0, 0, 0,
                                                               b2, 1, 1.0f, 0);
    // 7. LN2
    ln_wave<2><<<M / 4, 256, 0, stream>>>(feat, g2, be2);
    // 8. featT per batch: [S][H2] -> [H2][S]
    transpose_to_bf16<0><<<dim3(H2 / 32, S / 32, Bn), 256, 0, stream>>>(
        feat, featT, S, H2, (long)S * H2, (long)H2 * S);
    // 9. scores = feat @ feat^T / 32 -> d_out attn region (fp32), balanced triangle
    {
        const int NB = S / 128;              // 16
        const int nTri = NB * (NB + 1) / 2;  // 136
        gemm_nt<0><<<dim3(nTri * Bn, 1, 1), 256, 0, stream>>>(
            feat, feat, out_attn, S, S, H2, (long)S * H2, (long)S * H2, (long)S * S, nullptr, 0,
            0.03125f, 1);
    }
    // 10. softmax rows (fp32 in/out + bf16 copy)
    softmax_wave<<<M / 4, 256, 0, stream>>>(out_attn, attnb);
    // 11. attended = attn @ feat   [S,H2] bf16 per batch
    gemm_nt<1><<<dim3(H2 / 128, S / 128, Bn), 256, 0, stream>>>(attnb, featT, attd, S, H2, S,
                                                                (long)S * S, (long)H2 * S,
                                                                (long)S * H2, nullptr, 0, 1.0f,
                                                                0);
    // 12. head + logic gates + log (MFMA)
    head_kernel<<<M / 128, 256, 0, stream>>>(attd, WhT, bh, prior, ag, og, out_logits);
}

// Round 6
// 513.439 us; speedup vs baseline: 1.5290x; 1.0979x over previous
//
#include <hip/hip_runtime.h>

typedef unsigned short u16;
typedef __bf16 bf16x8 __attribute__((ext_vector_type(8)));
typedef float f32x4 __attribute__((ext_vector_type(4)));

__device__ __forceinline__ u16 f2bf(float f) {
    unsigned u = __float_as_uint(f);
    u = (u + 0x7FFFu + ((u >> 16) & 1u)) >> 16;
    return (u16)u;
}
__device__ __forceinline__ float bf2f(u16 h) {
    return __uint_as_float(((unsigned)h) << 16);
}

// async global -> LDS, 16B per lane
__device__ __forceinline__ void gld16(const u16* g, u16* l) {
    __builtin_amdgcn_global_load_lds((const __attribute__((address_space(1))) void*)g,
                                     (__attribute__((address_space(3))) void*)l, 16, 0, 0);
}

// st_16x32 subtiled swizzle for a [R][64] bf16 tile staged as 16x32 subtiles.
// short-address of logical (row, col); XOR bit4 (16 shorts) with row bit3.
__device__ __forceinline__ int swz(int row, int col) {
    return ((row >> 4) * 2 + (col >> 5)) * 512 + (row & 15) * 32 +
           ((col & 31) ^ ((row & 8) ? 16 : 0));
}

// ---------------- convert fp32 -> bf16 (flat) ----------------
__global__ __launch_bounds__(256) void cvt_kernel(const float* __restrict__ in,
                                                  u16* __restrict__ out, long n) {
    long i = ((long)blockIdx.x * blockDim.x + threadIdx.x) * 4;
    if (i + 3 < n) {
        float4 v = *(const float4*)&in[i];
        __align__(8) u16 r[4] = {f2bf(v.x), f2bf(v.y), f2bf(v.z), f2bf(v.w)};
        *(int2*)&out[i] = *(const int2*)r;
    }
}

// ---------------- transpose (+convert) -> bf16 ----------------
template <int INF32>
__global__ __launch_bounds__(256) void transpose_to_bf16(const void* __restrict__ in,
                                                         u16* __restrict__ out, int R, int C,
                                                         long inB, long outB) {
    __shared__ float tile[32][33];
    const long zi = (long)blockIdx.z * inB;
    const long zo = (long)blockIdx.z * outB;
    const int c0 = blockIdx.x * 32, r0 = blockIdx.y * 32;
    const int tx = threadIdx.x & 31;
    const int ty = threadIdx.x >> 5;  // 0..7
#pragma unroll
    for (int i = 0; i < 32; i += 8) {
        long idx = zi + (long)(r0 + ty + i) * C + c0 + tx;
        float v = INF32 ? ((const float*)in)[idx] : bf2f(((const u16*)in)[idx]);
        tile[ty + i][tx] = v;
    }
    __syncthreads();
#pragma unroll
    for (int i = 0; i < 32; i += 8) {
        out[zo + (long)(c0 + ty + i) * R + r0 + tx] = f2bf(tile[tx][ty + i]);
    }
}

// ---------------- 256x256 NT bf16 MFMA GEMM, counted-vmcnt pipeline ----------------
// C[M,N] = scale * (A[M,K] @ B[N,K]^T) + bias, optional relu.
// 8 waves (2Mx4N), BK=64, 128KB double-buffered LDS, st_16x32 swizzle
// (inverse-swizzled global source + swizzled ds_read), vmcnt(8) counted waits.
// symm: M==N, A==B per batch; grid.x = Bn*NB*(NB+1)/2; balanced triangle.
template <int OUTBF>
__global__ __launch_bounds__(512, 2) void gemm_nt(const u16* __restrict__ A,
                                                  const u16* __restrict__ Bm,
                                                  void* __restrict__ Cout, int M, int N, int K,
                                                  long sA, long sB, long sC,
                                                  const float* __restrict__ bias, int relu,
                                                  float scale, int symm) {
    int bx, by, zz;
    if (symm) {
        const int q = gridDim.x >> 3;
        const int orig = blockIdx.x;
        const int wgid = (orig & 7) * q + (orig >> 3);
        const int NB = N >> 8;
        const int nTri = (NB * (NB + 1)) >> 1;
        zz = wgid / nTri;
        int t = wgid - zz * nTri;
        by = 0;
        int rem = NB;
        while (t >= rem) {
            t -= rem;
            --rem;
            ++by;
        }
        bx = by + t;
    } else {
        const int nx = gridDim.x;
        const int nwg = nx * gridDim.y;
        const int orig = blockIdx.y * nx + blockIdx.x;
        const int q = nwg >> 3, r = nwg & 7, xcd = orig & 7, o8 = orig >> 3;
        const int wgid = (xcd < r ? xcd * (q + 1) : r * (q + 1) + (xcd - r) * q) + o8;
        bx = wgid % nx;
        by = wgid / nx;
        zz = blockIdx.z;
    }

    __shared__ __align__(16) u16 As[2][256 * 64];
    __shared__ __align__(16) u16 Bs[2][256 * 64];
    const int tid = threadIdx.x;  // 0..511
    const int lane = tid & 63;
    const int wid = tid >> 6;  // 0..7
    const int wr = wid >> 2;   // 0..1
    const int wc = wid & 3;    // 0..3
    const int l15 = lane & 15, lg = lane >> 4;
    const long zA = (long)zz * sA;
    const long zB = (long)zz * sB;
    const long zC = (long)zz * sC;
    const int m0 = by * 256, n0 = bx * 256;
    const u16* Ab = A + zA + (long)m0 * K;
    const u16* Bb = Bm + zB + (long)n0 * K;
    const int nt = K >> 6;

    f32x4 acc[8][4] = {};

    // staging: 2048 16B-chunks per operand tile; thread's chunk c = i*512+tid.
    // chunk c <- global (row, colbase..colbase+7) with inverse-swizzled colbase,
    // so that swizzled reads (swz) return the true element.
    auto stage = [&](int t, int b) {
#pragma unroll
        for (int i = 0; i < 4; ++i) {
            const int c = i * 512 + tid;
            const int s = c >> 6, r = (c >> 2) & 15;
            const int row = (s >> 1) * 16 + r;
            const int col = (s & 1) * 32 + (((c & 3) * 8) ^ ((r & 8) ? 16 : 0));
            gld16(Ab + (long)row * K + t * 64 + col, &As[b][c * 8]);
        }
#pragma unroll
        for (int i = 0; i < 4; ++i) {
            const int c = i * 512 + tid;
            const int s = c >> 6, r = (c >> 2) & 15;
            const int row = (s >> 1) * 16 + r;
            const int col = (s & 1) * 32 + (((c & 3) * 8) ^ ((r & 8) ? 16 : 0));
            gld16(Bb + (long)row * K + t * 64 + col, &Bs[b][c * 8]);
        }
    };

    stage(0, 0);
    for (int t = 0; t < nt; ++t) {
        const int cur = t & 1;
        if (t + 1 < nt) {
            stage(t + 1, cur ^ 1);
            asm volatile("s_waitcnt vmcnt(8)" ::: "memory");  // tile t landed; 8 in flight
        } else {
            asm volatile("s_waitcnt vmcnt(0)" ::: "memory");
        }
        __builtin_amdgcn_s_barrier();

        bf16x8 bf[4][2];
#pragma unroll
        for (int n = 0; n < 4; ++n)
#pragma unroll
            for (int kk = 0; kk < 2; ++kk)
                bf[n][kk] = *(const bf16x8*)&Bs[cur][swz(wc * 64 + n * 16 + l15, kk * 32 + lg * 8)];
#pragma unroll
        for (int mg = 0; mg < 4; ++mg) {
            bf16x8 af[2][2];
#pragma unroll
            for (int mi = 0; mi < 2; ++mi)
#pragma unroll
                for (int kk = 0; kk < 2; ++kk)
                    af[mi][kk] = *(const bf16x8*)&As[cur][swz(
                        wr * 128 + mg * 32 + mi * 16 + l15, kk * 32 + lg * 8)];
            __builtin_amdgcn_s_setprio(1);
#pragma unroll
            for (int mi = 0; mi < 2; ++mi)
#pragma unroll
                for (int n = 0; n < 4; ++n)
#pragma unroll
                    for (int kk = 0; kk < 2; ++kk)
                        acc[mg * 2 + mi][n] = __builtin_amdgcn_mfma_f32_16x16x32_bf16(
                            af[mi][kk], bf[n][kk], acc[mg * 2 + mi][n], 0, 0, 0);
            __builtin_amdgcn_s_setprio(0);
            __builtin_amdgcn_s_barrier();
        }
    }

#pragma unroll
    for (int n = 0; n < 4; ++n) {
        const int col = n0 + wc * 64 + n * 16 + l15;
        const float bv = bias ? bias[col] : 0.0f;
#pragma unroll
        for (int m = 0; m < 8; ++m) {
            const int rowb = m0 + wr * 128 + m * 16 + lg * 4;
            float v[4];
#pragma unroll
            for (int r = 0; r < 4; ++r) {
                float f = acc[m][n][r] * scale + bv;
                if (relu) f = fmaxf(f, 0.0f);
                v[r] = f;
                if (OUTBF)
                    ((u16*)Cout)[zC + (long)(rowb + r) * N + col] = f2bf(f);
                else
                    ((float*)Cout)[zC + (long)(rowb + r) * N + col] = f;
            }
            if (!OUTBF && symm && bx > by) {
                *(float4*)&((float*)Cout)[zC + (long)col * N + rowb] =
                    make_float4(v[0], v[1], v[2], v[3]);
            }
        }
    }
}

// ---------------- LayerNorm, wave-per-row (bf16 in/out, in-place) ----------------
template <int CH>
__global__ __launch_bounds__(256) void ln_wave(u16* __restrict__ x, const float* __restrict__ g,
                                               const float* __restrict__ be) {
    const int lane = threadIdx.x & 63;
    const int wid = threadIdx.x >> 6;
    const long row = (long)blockIdx.x * 4 + wid;
    u16* p = x + row * (CH * 512);
    __align__(16) u16 raw[CH][8];
    float s = 0.f, ss = 0.f;
#pragma unroll
    for (int c = 0; c < CH; ++c) {
        *(int4*)raw[c] = *(const int4*)&p[(c * 64 + lane) * 8];
#pragma unroll
        for (int j = 0; j < 8; ++j) {
            float f = bf2f(raw[c][j]);
            s += f;
            ss += f * f;
        }
    }
#pragma unroll
    for (int o = 1; o < 64; o <<= 1) {
        s += __shfl_xor(s, o);
        ss += __shfl_xor(ss, o);
    }
    const float inv = 1.0f / (float)(CH * 512);
    const float mu = s * inv;
    const float var = ss * inv - mu * mu;
    const float rs = rsqrtf(var + 1e-5f);
#pragma unroll
    for (int c = 0; c < CH; ++c) {
        const int base = (c * 64 + lane) * 8;
        float4 g0 = *(const float4*)&g[base];
        float4 g1 = *(const float4*)&g[base + 4];
        float4 b0 = *(const float4*)&be[base];
        float4 b1 = *(const float4*)&be[base + 4];
        float gv[8] = {g0.x, g0.y, g0.z, g0.w, g1.x, g1.y, g1.z, g1.w};
        float bv[8] = {b0.x, b0.y, b0.z, b0.w, b1.x, b1.y, b1.z, b1.w};
#pragma unroll
        for (int j = 0; j < 8; ++j)
            raw[c][j] = f2bf((bf2f(raw[c][j]) - mu) * rs * gv[j] + bv[j]);
        *(int4*)&p[base] = *(const int4*)raw[c];
    }
}

// ---------------- softmax, wave-per-row over S=2048, fp32 in/out + bf16 copy ----------
__global__ __launch_bounds__(256) void softmax_wave(float* __restrict__ a,
                                                    u16* __restrict__ ab) {
    const int lane = threadIdx.x & 63;
    const int wid = threadIdx.x >> 6;
    const long row = (long)blockIdx.x * 4 + wid;
    float* p = a + row * 2048;
    float v[4][8];
    float mx = -3.4e38f;
#pragma unroll
    for (int c = 0; c < 4; ++c) {
        const int base = (c * 64 + lane) * 8;
        *(float4*)&v[c][0] = *(const float4*)&p[base];
        *(float4*)&v[c][4] = *(const float4*)&p[base + 4];
#pragma unroll
        for (int j = 0; j < 8; ++j) mx = fmaxf(mx, v[c][j]);
    }
#pragma unroll
    for (int o = 1; o < 64; o <<= 1) mx = fmaxf(mx, __shfl_xor(mx, o));
    float s = 0.f;
#pragma unroll
    for (int c = 0; c < 4; ++c)
#pragma unroll
        for (int j = 0; j < 8; ++j) {
            v[c][j] = expf(v[c][j] - mx);
            s += v[c][j];
        }
#pragma unroll
    for (int o = 1; o < 64; o <<= 1) s += __shfl_xor(s, o);
    const float inv = 1.0f / s;
#pragma unroll
    for (int c = 0; c < 4; ++c) {
        const int base = (c * 64 + lane) * 8;
        __align__(16) u16 rb[8];
#pragma unroll
        for (int j = 0; j < 8; ++j) {
            v[c][j] *= inv;
            rb[j] = f2bf(v[c][j]);
        }
        *(float4*)&p[base] = *(const float4*)&v[c][0];
        *(float4*)&p[base + 4] = *(const float4*)&v[c][4];
        *(int4*)&ab[row * 2048 + base] = *(const int4*)rb;
    }
}

// ---------------- head: attended(bf16) @ WhT + bh -> gates -> log ----------------
__global__ __launch_bounds__(256) void head_kernel(const u16* __restrict__ A,
                                                   const u16* __restrict__ WhT,
                                                   const float* __restrict__ bh,
                                                   const float* __restrict__ prior,
                                                   const float* __restrict__ ag,
                                                   const float* __restrict__ og,
                                                   float* __restrict__ out) {
    __shared__ __align__(16) u16 As2[128 * 64];
    __shared__ __align__(16) u16 Bs2[64 * 64];
    const int tid = threadIdx.x;
    const int lane = tid & 63;
    const int wid = tid >> 6;
    const int l15 = lane & 15, lg = lane >> 4;
    const int m0 = blockIdx.x * 128;
    const int srow = tid >> 3, scol = (tid & 7) * 8;
    const u16* pa = A + (long)(m0 + srow) * 1024 + scol;
    const u16* pb = WhT + (long)srow * 1024 + scol;

    f32x4 acc[2][4] = {};
    for (int k0 = 0; k0 < 1024; k0 += 64) {
#pragma unroll
        for (int i = 0; i < 4; ++i) gld16(pa + (long)i * 32 * 1024 + k0, &As2[i * 2048 + tid * 8]);
#pragma unroll
        for (int i = 0; i < 2; ++i) gld16(pb + (long)i * 32 * 1024 + k0, &Bs2[i * 2048 + tid * 8]);
        __syncthreads();
#pragma unroll
        for (int kk = 0; kk < 2; ++kk) {
            bf16x8 af[2], bfr[4];
#pragma unroll
            for (int m = 0; m < 2; ++m)
                af[m] = *(const bf16x8*)&As2[(wid * 32 + m * 16 + l15) * 64 + kk * 32 + lg * 8];
#pragma unroll
            for (int n = 0; n < 4; ++n)
                bfr[n] = *(const bf16x8*)&Bs2[(n * 16 + l15) * 64 + kk * 32 + lg * 8];
#pragma unroll
            for (int m = 0; m < 2; ++m)
#pragma unroll
                for (int n = 0; n < 4; ++n)
                    acc[m][n] =
                        __builtin_amdgcn_mfma_f32_16x16x32_bf16(af[m], bfr[n], acc[m][n], 0, 0, 0);
        }
        __syncthreads();
    }

#pragma unroll
    for (int n = 0; n < 4; ++n) {
        const int col = n * 16 + l15;
        const float bhv = bh[col];
        const float agv = ag[col];
        const float ogv = og[col];
#pragma unroll
        for (int m = 0; m < 2; ++m) {
#pragma unroll
            for (int r = 0; r < 4; ++r) {
                const int row = m0 + wid * 32 + m * 16 + lg * 4 + r;
                const float logit = acc[m][n][r] + bhv;
                const int b = row >> 11;
                const float sp = 1.f / (1.f + expf(-prior[b * 64 + col]));
                const float sl = 1.f / (1.f + expf(-logit));
                const float av = fminf(sl, sp) * agv;
                const float ov = fmaxf(sl, sp) * ogv;
                out[(long)row * 64 + col] = logf((av + ov) * 0.5f + 1e-10f);
            }
        }
    }
}

extern "C" void kernel_launch(void* const* d_in, const int* in_sizes, int n_in, void* d_out,
                              int out_size, void* d_ws, size_t ws_size, hipStream_t stream) {
    const float* emb = (const float*)d_in[0];
    const float* prior = (const float*)d_in[1];
    const float* W1 = (const float*)d_in[2];
    const float* b1 = (const float*)d_in[3];
    const float* g1 = (const float*)d_in[4];
    const float* be1 = (const float*)d_in[5];
    const float* W2 = (const float*)d_in[6];
    const float* b2 = (const float*)d_in[7];
    const float* g2 = (const float*)d_in[8];
    const float* be2 = (const float*)d_in[9];
    const float* Wh = (const float*)d_in[10];
    const float* bh = (const float*)d_in[11];
    const float* ag = (const float*)d_in[12];
    const float* og = (const float*)d_in[13];

    const int Bn = 8, S = 2048, DIN = 1024, H1 = 2048, H2 = 1024, Cc = 64;
    const int M = Bn * S;  // 16384

    char* ws = (char*)d_ws;
    size_t off = 0;
    auto alloc = [&](size_t b) {
        size_t o = off;
        off += (b + 255) & ~(size_t)255;
        return o;
    };
    // Live-range-shared regions (peak ~136 MB):
    //   R0 (64MB): h (steps 4-6)      then attnb (steps 10-11)
    //   R1 (32MB): embb (steps 1-4)   then featT (steps 8-11)
    //   R2 (32MB): feat (steps 6-9)   then attd (steps 11-12)
    char* R0 = ws + alloc((size_t)M * H1 * 2);
    char* R1 = ws + alloc((size_t)M * DIN * 2);
    char* R2 = ws + alloc((size_t)M * H2 * 2);
    u16* W1t = (u16*)(ws + alloc((size_t)H1 * DIN * 2));
    u16* W2t = (u16*)(ws + alloc((size_t)H2 * H1 * 2));
    u16* WhT = (u16*)(ws + alloc((size_t)Cc * H2 * 2));

    u16* h = (u16*)R0;
    u16* attnb = (u16*)R0;
    u16* embb = (u16*)R1;
    u16* featT = (u16*)R1;
    u16* feat = (u16*)R2;
    u16* attd = (u16*)R2;

    float* out_logits = (float*)d_out;
    float* out_attn = out_logits + (size_t)M * Cc;

    // 1. embeddings -> bf16
    cvt_kernel<<<(int)(((long)M * DIN) / 1024), 256, 0, stream>>>(emb, embb, (long)M * DIN);
    // 2. W1 [DIN][H1] -> W1t [H1][DIN]
    transpose_to_bf16<1><<<dim3(H1 / 32, DIN / 32, 1), 256, 0, stream>>>(W1, W1t, DIN, H1, 0, 0);
    // 3. W2 [H1][H2] -> W2t [H2][H1]
    transpose_to_bf16<1><<<dim3(H2 / 32, H1 / 32, 1), 256, 0, stream>>>(W2, W2t, H1, H2, 0, 0);
    // 3b. Wh [H2][C] -> WhT [C][H2]
    transpose_to_bf16<1><<<dim3(Cc / 32, H2 / 32, 1), 256, 0, stream>>>(Wh, WhT, H2, Cc, 0, 0);
    // 4. h = relu(emb @ W1 + b1)   [M,H1] bf16
    gemm_nt<1><<<dim3(H1 / 256, M / 256, 1), 512, 0, stream>>>(embb, W1t, h, M, H1, DIN, 0, 0, 0,
                                                               b1, 1, 1.0f, 0);
    // 5. LN1 (wave-per-row)
    ln_wave<4><<<M / 4, 256, 0, stream>>>(h, g1, be1);
    // 6. feat = relu(h @ W2 + b2)  [M,H2] bf16
    gemm_nt<1><<<dim3(H2 / 256, M / 256, 1), 512, 0, stream>>>(h, W2t, feat, M, H2, H1, 0, 0, 0,
                                                               b2, 1, 1.0f, 0);
    // 7. LN2
    ln_wave<2><<<M / 4, 256, 0, stream>>>(feat, g2, be2);
    // 8. featT per batch: [S][H2] -> [H2][S]
    transpose_to_bf16<0><<<dim3(H2 / 32, S / 32, Bn), 256, 0, stream>>>(
        feat, featT, S, H2, (long)S * H2, (long)H2 * S);
    // 9. scores = feat @ feat^T / 32 -> d_out attn region (fp32), balanced triangle
    {
        const int NB = S / 256;              // 8
        const int nTri = NB * (NB + 1) / 2;  // 36
        gemm_nt<0><<<dim3(nTri * Bn, 1, 1), 512, 0, stream>>>(
            feat, feat, out_attn, S, S, H2, (long)S * H2, (long)S * H2, (long)S * S, nullptr, 0,
            0.03125f, 1);
    }
    // 10. softmax rows (fp32 in/out + bf16 copy)
    softmax_wave<<<M / 4, 256, 0, stream>>>(out_attn, attnb);
    // 11. attended = attn @ feat   [S,H2] bf16 per batch
    gemm_nt<1><<<dim3(H2 / 256, S / 256, Bn), 512, 0, stream>>>(attnb, featT, attd, S, H2, S,
                                                                (long)S * S, (long)H2 * S,
                                                                (long)S * H2, nullptr, 0, 1.0f,
                                                                0);
    // 12. head + logic gates + log (MFMA)
    head_kernel<<<M / 128, 256, 0, stream>>>(attd, WhT, bh, prior, ag, og, out_logits);
}

// Round 7
// 488.556 us; speedup vs baseline: 1.6068x; 1.0509x over previous
//
#include <hip/hip_runtime.h>

typedef unsigned short u16;
typedef __bf16 bf16x8 __attribute__((ext_vector_type(8)));
typedef float f32x4 __attribute__((ext_vector_type(4)));

__device__ __forceinline__ u16 f2bf(float f) {
    unsigned u = __float_as_uint(f);
    u = (u + 0x7FFFu + ((u >> 16) & 1u)) >> 16;
    return (u16)u;
}
__device__ __forceinline__ float bf2f(u16 h) {
    return __uint_as_float(((unsigned)h) << 16);
}

// async global -> LDS, 16B per lane
__device__ __forceinline__ void gld16(const u16* g, u16* l) {
    __builtin_amdgcn_global_load_lds((const __attribute__((address_space(1))) void*)g,
                                     (__attribute__((address_space(3))) void*)l, 16, 0, 0);
}

// st_16x32 subtiled swizzle for a [R][64] bf16 tile staged as 16x32 subtiles.
__device__ __forceinline__ int swz(int row, int col) {
    return ((row >> 4) * 2 + (col >> 5)) * 512 + (row & 15) * 32 +
           ((col & 31) ^ ((row & 8) ? 16 : 0));
}

// ---------------- convert fp32 -> bf16 (flat) ----------------
__global__ __launch_bounds__(256) void cvt_kernel(const float* __restrict__ in,
                                                  u16* __restrict__ out, long n) {
    long i = ((long)blockIdx.x * blockDim.x + threadIdx.x) * 4;
    if (i + 3 < n) {
        float4 v = *(const float4*)&in[i];
        __align__(8) u16 r[4] = {f2bf(v.x), f2bf(v.y), f2bf(v.z), f2bf(v.w)};
        *(int2*)&out[i] = *(const int2*)r;
    }
}

// ---------------- transpose (+convert) -> bf16 ----------------
template <int INF32>
__global__ __launch_bounds__(256) void transpose_to_bf16(const void* __restrict__ in,
                                                         u16* __restrict__ out, int R, int C,
                                                         long inB, long outB) {
    __shared__ float tile[32][33];
    const long zi = (long)blockIdx.z * inB;
    const long zo = (long)blockIdx.z * outB;
    const int c0 = blockIdx.x * 32, r0 = blockIdx.y * 32;
    const int tx = threadIdx.x & 31;
    const int ty = threadIdx.x >> 5;  // 0..7
#pragma unroll
    for (int i = 0; i < 32; i += 8) {
        long idx = zi + (long)(r0 + ty + i) * C + c0 + tx;
        float v = INF32 ? ((const float*)in)[idx] : bf2f(((const u16*)in)[idx]);
        tile[ty + i][tx] = v;
    }
    __syncthreads();
#pragma unroll
    for (int i = 0; i < 32; i += 8) {
        out[zo + (long)(c0 + ty + i) * R + r0 + tx] = f2bf(tile[tx][ty + i]);
    }
}

// ---------------- 256x256 NT bf16 MFMA GEMM, phase-pipelined counted-vmcnt ----------
// C[M,N] = scale * (A[M,K] @ B[N,K]^T) + bias, optional relu.
// 8 waves (2Mx4N), BK=64, 128KB double-buffered LDS, st_16x32 swizzle.
// Staging split into 4 chunks/tile interleaved with 4 MFMA phases; A-frag
// read-ahead by one phase; steady-state wait vmcnt(2); 2 barriers per K-tile.
template <int OUTBF>
__global__ __launch_bounds__(512, 2) void gemm_nt(const u16* __restrict__ A,
                                                  const u16* __restrict__ Bm,
                                                  void* __restrict__ Cout, int M, int N, int K,
                                                  long sA, long sB, long sC,
                                                  const float* __restrict__ bias, int relu,
                                                  float scale, int symm) {
    int bx, by, zz;
    if (symm) {
        const int q = gridDim.x >> 3;
        const int orig = blockIdx.x;
        const int wgid = (orig & 7) * q + (orig >> 3);
        const int NB = N >> 8;
        const int nTri = (NB * (NB + 1)) >> 1;
        zz = wgid / nTri;
        int t = wgid - zz * nTri;
        by = 0;
        int rem = NB;
        while (t >= rem) {
            t -= rem;
            --rem;
            ++by;
        }
        bx = by + t;
    } else {
        const int nx = gridDim.x;
        const int nwg = nx * gridDim.y;
        const int orig = blockIdx.y * nx + blockIdx.x;
        const int q = nwg >> 3, r = nwg & 7, xcd = orig & 7, o8 = orig >> 3;
        const int wgid = (xcd < r ? xcd * (q + 1) : r * (q + 1) + (xcd - r) * q) + o8;
        bx = wgid % nx;
        by = wgid / nx;
        zz = blockIdx.z;
    }

    __shared__ __align__(16) u16 As[2][256 * 64];
    __shared__ __align__(16) u16 Bs[2][256 * 64];
    const int tid = threadIdx.x;  // 0..511
    const int lane = tid & 63;
    const int wid = tid >> 6;  // 0..7
    const int wr = wid >> 2;   // 0..1
    const int wc = wid & 3;    // 0..3
    const int l15 = lane & 15, lg = lane >> 4;
    const long zA = (long)zz * sA;
    const long zB = (long)zz * sB;
    const long zC = (long)zz * sC;
    const int m0 = by * 256, n0 = bx * 256;
    const u16* Ab = A + zA + (long)m0 * K;
    const u16* Bb = Bm + zB + (long)n0 * K;
    const int nt = K >> 6;

    f32x4 acc[8][4] = {};

    // one chunk = 2 gld16/thread (1KB/wave into A + 1KB into B); 4 chunks/tile.
    auto stage_chunk = [&](int t, int b, int j) {
        const int c = j * 512 + tid;
        const int s = c >> 6, r = (c >> 2) & 15;
        const int row = (s >> 1) * 16 + r;
        const int col = (s & 1) * 32 + (((c & 3) * 8) ^ ((r & 8) ? 16 : 0));
        gld16(Ab + (long)row * K + t * 64 + col, &As[b][c * 8]);
        gld16(Bb + (long)row * K + t * 64 + col, &Bs[b][c * 8]);
    };

#pragma unroll
    for (int j = 0; j < 4; ++j) stage_chunk(0, 0, j);
    if (nt > 1) {
        stage_chunk(1, 1, 0);
        asm volatile("s_waitcnt vmcnt(2)" ::: "memory");
    } else {
        asm volatile("s_waitcnt vmcnt(0)" ::: "memory");
    }
    __builtin_amdgcn_s_barrier();

    for (int t = 0; t < nt; ++t) {
        const int cur = t & 1;
        bf16x8 bf[4][2];
#pragma unroll
        for (int n = 0; n < 4; ++n)
#pragma unroll
            for (int kk = 0; kk < 2; ++kk)
                bf[n][kk] = *(const bf16x8*)&Bs[cur][swz(wc * 64 + n * 16 + l15, kk * 32 + lg * 8)];
        bf16x8 af[2][2][2];
#pragma unroll
        for (int mi = 0; mi < 2; ++mi)
#pragma unroll
            for (int kk = 0; kk < 2; ++kk)
                af[0][mi][kk] =
                    *(const bf16x8*)&As[cur][swz(wr * 128 + mi * 16 + l15, kk * 32 + lg * 8)];
#pragma unroll
        for (int mg = 0; mg < 4; ++mg) {
            if (mg < 3) {
#pragma unroll
                for (int mi = 0; mi < 2; ++mi)
#pragma unroll
                    for (int kk = 0; kk < 2; ++kk)
                        af[(mg + 1) & 1][mi][kk] = *(const bf16x8*)&As[cur][swz(
                            wr * 128 + (mg + 1) * 32 + mi * 16 + l15, kk * 32 + lg * 8)];
                if (t + 1 < nt) stage_chunk(t + 1, cur ^ 1, mg + 1);
            }
            __builtin_amdgcn_s_setprio(1);
#pragma unroll
            for (int mi = 0; mi < 2; ++mi)
#pragma unroll
                for (int n = 0; n < 4; ++n)
#pragma unroll
                    for (int kk = 0; kk < 2; ++kk)
                        acc[mg * 2 + mi][n] = __builtin_amdgcn_mfma_f32_16x16x32_bf16(
                            af[mg & 1][mi][kk], bf[n][kk], acc[mg * 2 + mi][n], 0, 0, 0);
            __builtin_amdgcn_s_setprio(0);
        }
        // transition: free buf cur, prefetch chunk0 of tile t+2 into it, publish cur^1
        __builtin_amdgcn_s_barrier();
        if (t + 2 < nt) {
            stage_chunk(t + 2, cur, 0);
            asm volatile("s_waitcnt vmcnt(2)" ::: "memory");
        } else {
            asm volatile("s_waitcnt vmcnt(0)" ::: "memory");
        }
        __builtin_amdgcn_s_barrier();
    }

#pragma unroll
    for (int n = 0; n < 4; ++n) {
        const int col = n0 + wc * 64 + n * 16 + l15;
        const float bv = bias ? bias[col] : 0.0f;
#pragma unroll
        for (int m = 0; m < 8; ++m) {
            const int rowb = m0 + wr * 128 + m * 16 + lg * 4;
            float v[4];
#pragma unroll
            for (int r = 0; r < 4; ++r) {
                float f = acc[m][n][r] * scale + bv;
                if (relu) f = fmaxf(f, 0.0f);
                v[r] = f;
                if (OUTBF)
                    ((u16*)Cout)[zC + (long)(rowb + r) * N + col] = f2bf(f);
                else
                    ((float*)Cout)[zC + (long)(rowb + r) * N + col] = f;
            }
            if (!OUTBF && symm && bx > by) {
                *(float4*)&((float*)Cout)[zC + (long)col * N + rowb] =
                    make_float4(v[0], v[1], v[2], v[3]);
            }
        }
    }
}

// ---------------- LayerNorm, wave-per-row (bf16 in/out, in-place) ----------------
template <int CH>
__global__ __launch_bounds__(256) void ln_wave(u16* __restrict__ x, const float* __restrict__ g,
                                               const float* __restrict__ be) {
    const int lane = threadIdx.x & 63;
    const int wid = threadIdx.x >> 6;
    const long row = (long)blockIdx.x * 4 + wid;
    u16* p = x + row * (CH * 512);
    __align__(16) u16 raw[CH][8];
    float s = 0.f, ss = 0.f;
#pragma unroll
    for (int c = 0; c < CH; ++c) {
        *(int4*)raw[c] = *(const int4*)&p[(c * 64 + lane) * 8];
#pragma unroll
        for (int j = 0; j < 8; ++j) {
            float f = bf2f(raw[c][j]);
            s += f;
            ss += f * f;
        }
    }
#pragma unroll
    for (int o = 1; o < 64; o <<= 1) {
        s += __shfl_xor(s, o);
        ss += __shfl_xor(ss, o);
    }
    const float inv = 1.0f / (float)(CH * 512);
    const float mu = s * inv;
    const float var = ss * inv - mu * mu;
    const float rs = rsqrtf(var + 1e-5f);
#pragma unroll
    for (int c = 0; c < CH; ++c) {
        const int base = (c * 64 + lane) * 8;
        float4 g0 = *(const float4*)&g[base];
        float4 g1 = *(const float4*)&g[base + 4];
        float4 b0 = *(const float4*)&be[base];
        float4 b1 = *(const float4*)&be[base + 4];
        float gv[8] = {g0.x, g0.y, g0.z, g0.w, g1.x, g1.y, g1.z, g1.w};
        float bv[8] = {b0.x, b0.y, b0.z, b0.w, b1.x, b1.y, b1.z, b1.w};
#pragma unroll
        for (int j = 0; j < 8; ++j)
            raw[c][j] = f2bf((bf2f(raw[c][j]) - mu) * rs * gv[j] + bv[j]);
        *(int4*)&p[base] = *(const int4*)raw[c];
    }
}

// ---------------- softmax, wave-per-row over S=2048, fp32 in/out + bf16 copy ----------
__global__ __launch_bounds__(256) void softmax_wave(float* __restrict__ a,
                                                    u16* __restrict__ ab) {
    const int lane = threadIdx.x & 63;
    const int wid = threadIdx.x >> 6;
    const long row = (long)blockIdx.x * 4 + wid;
    float* p = a + row * 2048;
    float v[4][8];
    float mx = -3.4e38f;
#pragma unroll
    for (int c = 0; c < 4; ++c) {
        const int base = (c * 64 + lane) * 8;
        *(float4*)&v[c][0] = *(const float4*)&p[base];
        *(float4*)&v[c][4] = *(const float4*)&p[base + 4];
#pragma unroll
        for (int j = 0; j < 8; ++j) mx = fmaxf(mx, v[c][j]);
    }
#pragma unroll
    for (int o = 1; o < 64; o <<= 1) mx = fmaxf(mx, __shfl_xor(mx, o));
    float s = 0.f;
#pragma unroll
    for (int c = 0; c < 4; ++c)
#pragma unroll
        for (int j = 0; j < 8; ++j) {
            v[c][j] = expf(v[c][j] - mx);
            s += v[c][j];
        }
#pragma unroll
    for (int o = 1; o < 64; o <<= 1) s += __shfl_xor(s, o);
    const float inv = 1.0f / s;
#pragma unroll
    for (int c = 0; c < 4; ++c) {
        const int base = (c * 64 + lane) * 8;
        __align__(16) u16 rb[8];
#pragma unroll
        for (int j = 0; j < 8; ++j) {
            v[c][j] *= inv;
            rb[j] = f2bf(v[c][j]);
        }
        *(float4*)&p[base] = *(const float4*)&v[c][0];
        *(float4*)&p[base + 4] = *(const float4*)&v[c][4];
        *(int4*)&ab[row * 2048 + base] = *(const int4*)rb;
    }
}

// ---------------- head: attended(bf16) @ WhT + bh -> gates -> log ----------------
__global__ __launch_bounds__(256) void head_kernel(const u16* __restrict__ A,
                                                   const u16* __restrict__ WhT,
                                                   const float* __restrict__ bh,
                                                   const float* __restrict__ prior,
                                                   const float* __restrict__ ag,
                                                   const float* __restrict__ og,
                                                   float* __restrict__ out) {
    __shared__ __align__(16) u16 As2[128 * 64];
    __shared__ __align__(16) u16 Bs2[64 * 64];
    const int tid = threadIdx.x;
    const int lane = tid & 63;
    const int wid = tid >> 6;
    const int l15 = lane & 15, lg = lane >> 4;
    const int m0 = blockIdx.x * 128;
    const int srow = tid >> 3, scol = (tid & 7) * 8;
    const u16* pa = A + (long)(m0 + srow) * 1024 + scol;
    const u16* pb = WhT + (long)srow * 1024 + scol;

    f32x4 acc[2][4] = {};
    for (int k0 = 0; k0 < 1024; k0 += 64) {
#pragma unroll
        for (int i = 0; i < 4; ++i) gld16(pa + (long)i * 32 * 1024 + k0, &As2[i * 2048 + tid * 8]);
#pragma unroll
        for (int i = 0; i < 2; ++i) gld16(pb + (long)i * 32 * 1024 + k0, &Bs2[i * 2048 + tid * 8]);
        __syncthreads();
#pragma unroll
        for (int kk = 0; kk < 2; ++kk) {
            bf16x8 af[2], bfr[4];
#pragma unroll
            for (int m = 0; m < 2; ++m)
                af[m] = *(const bf16x8*)&As2[(wid * 32 + m * 16 + l15) * 64 + kk * 32 + lg * 8];
#pragma unroll
            for (int n = 0; n < 4; ++n)
                bfr[n] = *(const bf16x8*)&Bs2[(n * 16 + l15) * 64 + kk * 32 + lg * 8];
#pragma unroll
            for (int m = 0; m < 2; ++m)
#pragma unroll
                for (int n = 0; n < 4; ++n)
                    acc[m][n] =
                        __builtin_amdgcn_mfma_f32_16x16x32_bf16(af[m], bfr[n], acc[m][n], 0, 0, 0);
        }
        __syncthreads();
    }

#pragma unroll
    for (int n = 0; n < 4; ++n) {
        const int col = n * 16 + l15;
        const float bhv = bh[col];
        const float agv = ag[col];
        const float ogv = og[col];
#pragma unroll
        for (int m = 0; m < 2; ++m) {
#pragma unroll
            for (int r = 0; r < 4; ++r) {
                const int row = m0 + wid * 32 + m * 16 + lg * 4 + r;
                const float logit = acc[m][n][r] + bhv;
                const int b = row >> 11;
                const float sp = 1.f / (1.f + expf(-prior[b * 64 + col]));
                const float sl = 1.f / (1.f + expf(-logit));
                const float av = fminf(sl, sp) * agv;
                const float ov = fmaxf(sl, sp) * ogv;
                out[(long)row * 64 + col] = logf((av + ov) * 0.5f + 1e-10f);
            }
        }
    }
}

extern "C" void kernel_launch(void* const* d_in, const int* in_sizes, int n_in, void* d_out,
                              int out_size, void* d_ws, size_t ws_size, hipStream_t stream) {
    const float* emb = (const float*)d_in[0];
    const float* prior = (const float*)d_in[1];
    const float* W1 = (const float*)d_in[2];
    const float* b1 = (const float*)d_in[3];
    const float* g1 = (const float*)d_in[4];
    const float* be1 = (const float*)d_in[5];
    const float* W2 = (const float*)d_in[6];
    const float* b2 = (const float*)d_in[7];
    const float* g2 = (const float*)d_in[8];
    const float* be2 = (const float*)d_in[9];
    const float* Wh = (const float*)d_in[10];
    const float* bh = (const float*)d_in[11];
    const float* ag = (const float*)d_in[12];
    const float* og = (const float*)d_in[13];

    const int Bn = 8, S = 2048, DIN = 1024, H1 = 2048, H2 = 1024, Cc = 64;
    const int M = Bn * S;  // 16384

    char* ws = (char*)d_ws;
    size_t off = 0;
    auto alloc = [&](size_t b) {
        size_t o = off;
        off += (b + 255) & ~(size_t)255;
        return o;
    };
    // Live-range-shared regions (peak ~136 MB):
    //   R0 (64MB): h (steps 4-6)      then attnb (steps 10-11)
    //   R1 (32MB): embb (steps 1-4)   then featT (steps 8-11)
    //   R2 (32MB): feat (steps 6-9)   then attd (steps 11-12)
    char* R0 = ws + alloc((size_t)M * H1 * 2);
    char* R1 = ws + alloc((size_t)M * DIN * 2);
    char* R2 = ws + alloc((size_t)M * H2 * 2);
    u16* W1t = (u16*)(ws + alloc((size_t)H1 * DIN * 2));
    u16* W2t = (u16*)(ws + alloc((size_t)H2 * H1 * 2));
    u16* WhT = (u16*)(ws + alloc((size_t)Cc * H2 * 2));

    u16* h = (u16*)R0;
    u16* attnb = (u16*)R0;
    u16* embb = (u16*)R1;
    u16* featT = (u16*)R1;
    u16* feat = (u16*)R2;
    u16* attd = (u16*)R2;

    float* out_logits = (float*)d_out;
    float* out_attn = out_logits + (size_t)M * Cc;

    // 1. embeddings -> bf16
    cvt_kernel<<<(int)(((long)M * DIN) / 1024), 256, 0, stream>>>(emb, embb, (long)M * DIN);
    // 2. W1 [DIN][H1] -> W1t [H1][DIN]
    transpose_to_bf16<1><<<dim3(H1 / 32, DIN / 32, 1), 256, 0, stream>>>(W1, W1t, DIN, H1, 0, 0);
    // 3. W2 [H1][H2] -> W2t [H2][H1]
    transpose_to_bf16<1><<<dim3(H2 / 32, H1 / 32, 1), 256, 0, stream>>>(W2, W2t, H1, H2, 0, 0);
    // 3b. Wh [H2][C] -> WhT [C][H2]
    transpose_to_bf16<1><<<dim3(Cc / 32, H2 / 32, 1), 256, 0, stream>>>(Wh, WhT, H2, Cc, 0, 0);
    // 4. h = relu(emb @ W1 + b1)   [M,H1] bf16
    gemm_nt<1><<<dim3(H1 / 256, M / 256, 1), 512, 0, stream>>>(embb, W1t, h, M, H1, DIN, 0, 0, 0,
                                                               b1, 1, 1.0f, 0);
    // 5. LN1 (wave-per-row)
    ln_wave<4><<<M / 4, 256, 0, stream>>>(h, g1, be1);
    // 6. feat = relu(h @ W2 + b2)  [M,H2] bf16
    gemm_nt<1><<<dim3(H2 / 256, M / 256, 1), 512, 0, stream>>>(h, W2t, feat, M, H2, H1, 0, 0, 0,
                                                               b2, 1, 1.0f, 0);
    // 7. LN2
    ln_wave<2><<<M / 4, 256, 0, stream>>>(feat, g2, be2);
    // 8. featT per batch: [S][H2] -> [H2][S]
    transpose_to_bf16<0><<<dim3(H2 / 32, S / 32, Bn), 256, 0, stream>>>(
        feat, featT, S, H2, (long)S * H2, (long)H2 * S);
    // 9. scores = feat @ feat^T / 32 -> d_out attn region (fp32), balanced triangle
    {
        const int NB = S / 256;              // 8
        const int nTri = NB * (NB + 1) / 2;  // 36
        gemm_nt<0><<<dim3(nTri * Bn, 1, 1), 512, 0, stream>>>(
            feat, feat, out_attn, S, S, H2, (long)S * H2, (long)S * H2, (long)S * S, nullptr, 0,
            0.03125f, 1);
    }
    // 10. softmax rows (fp32 in/out + bf16 copy)
    softmax_wave<<<M / 4, 256, 0, stream>>>(out_attn, attnb);
    // 11. attended = attn @ feat   [S,H2] bf16 per batch
    gemm_nt<1><<<dim3(H2 / 256, S / 256, Bn), 512, 0, stream>>>(attnb, featT, attd, S, H2, S,
                                                                (long)S * S, (long)H2 * S,
                                                                (long)S * H2, nullptr, 0, 1.0f,
                                                                0);
    // 12. head + logic gates + log (MFMA)
    head_kernel<<<M / 128, 256, 0, stream>>>(attd, WhT, bh, prior, ag, og, out_logits);
}